// Round 9
// baseline (332.650 us; speedup 1.0000x reference)
//
#include <hip/hip_runtime.h>
#include <math.h>

// ---------------------------------------------------------------------------
// UltraMem forward, MI355X. B=2 N=1024 DIM=1024 DQK=128 NUM_KEYS=256 TOPK=32
// RANK=2 HEADS=2 DV=512 KCONV=5.
// R9: tail reverted to R7 (R8's intra-block pipeline lost to cross-block TLP:
// occupancy 56%->20% at same BW). ATTRIBUTION: convgemm1 x3 and gemm2ln x3
// (idempotent). (t_cg1 + t_g2ln) = (dur - 273.7)/2 -> decides R10: optimize
// the GEMMs vs fuse launches.
// ---------------------------------------------------------------------------

#define ROWS 2048            // B*N
#define KSPLIT 8             // gemm1 K partitions

// ======================= 2x2 SVD (LAPACK dgesdd replica) ====================
__device__ inline double dsgn(double x, double y) { return (y >= 0.0) ? fabs(x) : -fabs(x); }

__device__ void dlasv2_dev(double f, double g, double h,
                           double& ssmin, double& ssmax,
                           double& snr, double& csr, double& snl, double& csl)
{
  const double EPSD = 2.2204460492503131e-16;
  double ft = f, fa = fabs(f), ht = h, ha = fabs(h);
  int pmax = 1;
  bool swp = (ha > fa);
  if (swp) { pmax = 3; double tp = ft; ft = ht; ht = tp; tp = fa; fa = ha; ha = tp; }
  double gt = g, ga = fabs(gt);
  double clt = 0.0, crt = 0.0, slt = 0.0, srt = 0.0;
  if (ga == 0.0) {
    ssmin = ha; ssmax = fa; clt = 1.0; crt = 1.0; slt = 0.0; srt = 0.0;
  } else {
    bool gasmal = true;
    if (ga > fa) {
      pmax = 2;
      if ((fa / ga) < EPSD) {
        gasmal = false;
        ssmax = ga;
        if (ha > 1.0) ssmin = fa / (ga / ha); else ssmin = (fa / ga) * ha;
        clt = 1.0; slt = ht / gt; srt = 1.0; crt = ft / gt;
      }
    }
    if (gasmal) {
      double dd = fa - ha, l;
      if (dd == fa) l = 1.0; else l = dd / fa;
      double m  = gt / ft;
      double t  = 2.0 - l;
      double mm = m * m, tt = t * t;
      double s  = sqrt(tt + mm);
      double r  = (l == 0.0) ? fabs(m) : sqrt(l * l + mm);
      double a  = 0.5 * (s + r);
      ssmin = ha / a;
      ssmax = fa * a;
      if (mm == 0.0) {
        if (l == 0.0) t = dsgn(2.0, ft) * dsgn(1.0, gt);
        else          t = gt / dsgn(dd, ft) + m / t;
      } else {
        t = (m / (s + t) + m / (r + l)) * (1.0 + a);
      }
      double ll = sqrt(t * t + 4.0);
      crt = 2.0 / ll;
      srt = t / ll;
      clt = (crt + srt * m) / a;
      slt = (ht / ft) * srt / a;
    }
  }
  if (swp) { csl = srt; snl = crt; csr = slt; snr = clt; }
  else     { csl = clt; snl = slt; csr = crt; snr = srt; }
  double tsign = 1.0;
  if (pmax == 1) tsign = dsgn(1.0, csr) * dsgn(1.0, csl) * dsgn(1.0, f);
  if (pmax == 2) tsign = dsgn(1.0, snr) * dsgn(1.0, csl) * dsgn(1.0, g);
  if (pmax == 3) tsign = dsgn(1.0, snr) * dsgn(1.0, snl) * dsgn(1.0, h);
  ssmax = dsgn(ssmax, tsign);
  ssmin = dsgn(ssmin, tsign * dsgn(1.0, f) * dsgn(1.0, h));
}

__device__ void do_svd(const float* __restrict__ core, float* __restrict__ misc,
                       float* __restrict__ aux_out)
{
  double aux = 0.0;
  for (int hh = 0; hh < 2; hh++) {
    double a = (double)core[hh * 4 + 0];
    double b = (double)core[hh * 4 + 1];
    double c = (double)core[hh * 4 + 2];
    double d = (double)core[hh * 4 + 3];
    double tau = 0.0, v2 = 0.0, d1, e, d2;
    if (c != 0.0) {
      double nrm  = sqrt(a * a + c * c);
      double beta = (a >= 0.0) ? -nrm : nrm;
      tau = (beta - a) / beta;
      v2  = c / (a - beta);
      double wsum = b + v2 * d;
      d1 = beta;
      e  = b - tau * wsum;
      d2 = d - tau * v2 * wsum;
    } else { d1 = a; e = b; d2 = d; }
    double ssmin, ssmax, snr, csr, snl, csl;
    dlasv2_dev(d1, e, d2, ssmin, ssmax, snr, csr, snl, csl);
    double t0 = csl + v2 * snl;
    double u0 = csl - tau * t0;
    double u1 = snl - tau * v2 * t0;
    double sg = (ssmax < 0.0) ? -1.0 : 1.0;
    misc[hh * 2 + 0]     = (float)u0;
    misc[hh * 2 + 1]     = (float)u1;
    misc[4 + hh * 2 + 0] = (float)(sg * csr);
    misc[4 + hh * 2 + 1] = (float)(sg * snr);
    double s2 = fabs(ssmin);
    double rl = s2 - 0.15; if (rl < 0.0) rl = 0.0;
    aux += rl * rl;
  }
  aux_out[0] = (float)(aux * 0.1);
}

// ================== K0: per-row RMS inv_s (8 rows/block) + SVD ==============
__global__ __launch_bounds__(256) void rms_kernel(const float* __restrict__ tokens,
                                                  const float* __restrict__ core,
                                                  float* __restrict__ inv_sg,
                                                  float* __restrict__ misc,
                                                  float* __restrict__ aux_out)
{
  __shared__ float red[8][4];
  const int t    = threadIdx.x;
  const int row0 = blockIdx.x * 8;
  const int c0   = t * 4;
  float sq[8];
  #pragma unroll
  for (int s = 0; s < 8; s++) {
    float4 v = *(const float4*)(tokens + (size_t)(row0 + s) * 1024 + c0);
    sq[s] = v.x * v.x + v.y * v.y + v.z * v.z + v.w * v.w;
  }
  #pragma unroll
  for (int off = 32; off; off >>= 1) {
    #pragma unroll
    for (int s = 0; s < 8; s++) sq[s] += __shfl_down(sq[s], off, 64);
  }
  const int lane = t & 63, w = t >> 6;
  if (lane == 0) {
    #pragma unroll
    for (int s = 0; s < 8; s++) red[s][w] = sq[s];
  }
  __syncthreads();
  if (t < 8)
    inv_sg[row0 + t] = rsqrtf((red[t][0] + red[t][1] + red[t][2] + red[t][3])
                              * (1.0f / 1024.0f) + 1.1920929e-07f);
  if (blockIdx.x == 0 && t == 0) do_svd(core, misc, aux_out);
}

// ===== K1: fused conv + gemm1, 32-row tiles. grid (64, KSPLIT). =============
__global__ __launch_bounds__(256) void convgemm1_kernel(
    const float* __restrict__ tokens, const float* __restrict__ inv_sg,
    const float* __restrict__ rms_w,  const float* __restrict__ conv_w,
    const float* __restrict__ conv_b, const float* __restrict__ wq,
    float* __restrict__ qpart)
{
  __shared__ float xh[36 * 33];                    // [srow][c], stride 33
  __shared__ __align__(16) float a_lds[32 * 32];   // [k][row]
  __shared__ __align__(16) float b_lds[32 * 128];  // [k][col]
  __shared__ float inv_l[36];
  const int t  = threadIdx.x;
  const int rb = blockIdx.x * 32;
  const int kb = blockIdx.y * 128;
  const int n0 = rb & 1023;          // 32-aligned => whole block same batch

  if (t < 36) inv_l[t] = (n0 - 4 + t >= 0) ? inv_sg[rb - 4 + t] : 0.0f;

  const int tx = t & 31, ty = t >> 5;
  const int c0g = tx * 4, r0 = ty * 4;
  float acc[4][4];
  #pragma unroll
  for (int i = 0; i < 4; i++)
    #pragma unroll
    for (int j = 0; j < 4; j++) acc[i][j] = 0.0f;

  const int ob = t >> 1, kqb = (t & 1) * 16;   // wq staging map
  const int cr = t & 31;                       // conv: row
  const int ch = (t >> 5) * 4;                 // conv: col base (4 cols/thread)

  for (int kt = 0; kt < 4; kt++) {
    const int k0 = kb + kt * 32;
    __syncthreads();                 // prev GEMM done before overwriting LDS
    #pragma unroll
    for (int it = 0; it < 2; it++) {
      int idx  = it * 256 + t;
      int srow = idx >> 3, f4 = (idx & 7) * 4;
      if (srow < 36) {
        float4 v = make_float4(0.f, 0.f, 0.f, 0.f);
        if (n0 - 4 + srow >= 0)
          v = *(const float4*)(tokens + (size_t)(rb - 4 + srow) * 1024 + k0 + f4);
        float iv = inv_l[srow];
        xh[srow * 33 + f4 + 0] = v.x * iv;
        xh[srow * 33 + f4 + 1] = v.y * iv;
        xh[srow * 33 + f4 + 2] = v.z * iv;
        xh[srow * 33 + f4 + 3] = v.w * iv;
      }
    }
    {
      const float* bp = wq + (size_t)ob * 1024 + k0 + kqb;
      float4 b0 = *(const float4*)(bp);
      float4 b1 = *(const float4*)(bp + 4);
      float4 b2 = *(const float4*)(bp + 8);
      float4 b3 = *(const float4*)(bp + 12);
      b_lds[(kqb +  0) * 128 + ob] = b0.x;  b_lds[(kqb +  1) * 128 + ob] = b0.y;
      b_lds[(kqb +  2) * 128 + ob] = b0.z;  b_lds[(kqb +  3) * 128 + ob] = b0.w;
      b_lds[(kqb +  4) * 128 + ob] = b1.x;  b_lds[(kqb +  5) * 128 + ob] = b1.y;
      b_lds[(kqb +  6) * 128 + ob] = b1.z;  b_lds[(kqb +  7) * 128 + ob] = b1.w;
      b_lds[(kqb +  8) * 128 + ob] = b2.x;  b_lds[(kqb +  9) * 128 + ob] = b2.y;
      b_lds[(kqb + 10) * 128 + ob] = b2.z;  b_lds[(kqb + 11) * 128 + ob] = b2.w;
      b_lds[(kqb + 12) * 128 + ob] = b3.x;  b_lds[(kqb + 13) * 128 + ob] = b3.y;
      b_lds[(kqb + 14) * 128 + ob] = b3.z;  b_lds[(kqb + 15) * 128 + ob] = b3.w;
    }
    __syncthreads();
    #pragma unroll
    for (int i = 0; i < 4; i++) {
      const int c = ch + i;
      const float* cw = conv_w + (size_t)(k0 + c) * 5;
      float a = xh[(cr + 0) * 33 + c] * cw[0]
              + xh[(cr + 1) * 33 + c] * cw[1]
              + xh[(cr + 2) * 33 + c] * cw[2]
              + xh[(cr + 3) * 33 + c] * cw[3]
              + xh[(cr + 4) * 33 + c] * cw[4];
      a_lds[c * 32 + cr] = a * rms_w[k0 + c] + conv_b[k0 + c];
    }
    __syncthreads();
    #pragma unroll
    for (int k = 0; k < 32; k++) {
      float4 av = *(const float4*)(a_lds + k * 32 + r0);
      float4 bv = *(const float4*)(b_lds + k * 128 + c0g);
      float ar[4] = {av.x, av.y, av.z, av.w};
      float br[4] = {bv.x, bv.y, bv.z, bv.w};
      #pragma unroll
      for (int i = 0; i < 4; i++)
        #pragma unroll
        for (int j = 0; j < 4; j++)
          acc[i][j] = fmaf(ar[i], br[j], acc[i][j]);
    }
  }
  float* C = qpart + (size_t)blockIdx.y * (ROWS * 128);
  #pragma unroll
  for (int i = 0; i < 4; i++) {
    float4 o4; o4.x = acc[i][0]; o4.y = acc[i][1]; o4.z = acc[i][2]; o4.w = acc[i][3];
    *(float4*)(C + (size_t)(rb + r0 + i) * 128 + c0g) = o4;
  }
}

// ========== K2: gemm2 with fused plane-reduce + LayerNorm (A side) =========
__global__ __launch_bounds__(256) void gemm2ln_kernel(const float* __restrict__ qpart,
                                                      const float* __restrict__ qln_w,
                                                      const float* __restrict__ keys,
                                                      float* __restrict__ C)
{
  __shared__ __align__(16) float a_l[128 * 32];     // [k][row], normalized
  __shared__ __align__(16) float b_lds[32 * 128];   // [k][col]
  const int t  = threadIdx.x;
  const int rb = blockIdx.x * 32;
  const int cb = blockIdx.y * 128;

  const int l32 = t & 31;          // k cols l32*4 .. +3
  const int g32 = t >> 5;          // rows g32 + 8*j
  float vs[4][4];
  #pragma unroll
  for (int j = 0; j < 4; j++) { vs[j][0]=0.f; vs[j][1]=0.f; vs[j][2]=0.f; vs[j][3]=0.f; }
  #pragma unroll
  for (int g = 0; g < KSPLIT; g++) {
    const float* pg = qpart + (size_t)g * (ROWS * 128) + (size_t)rb * 128 + l32 * 4;
    #pragma unroll
    for (int j = 0; j < 4; j++) {
      float4 v = *(const float4*)(pg + (g32 + 8 * j) * 128);
      vs[j][0] += v.x; vs[j][1] += v.y; vs[j][2] += v.z; vs[j][3] += v.w;
    }
  }
  float4 qw = *(const float4*)(qln_w + l32 * 4);
  #pragma unroll
  for (int j = 0; j < 4; j++) {
    float s1 = vs[j][0] + vs[j][1] + vs[j][2] + vs[j][3];
    #pragma unroll
    for (int off = 16; off; off >>= 1) s1 += __shfl_xor(s1, off, 32);
    float mu = s1 * (1.0f / 128.0f);
    float d0 = vs[j][0] - mu, d1 = vs[j][1] - mu, d2 = vs[j][2] - mu, d3 = vs[j][3] - mu;
    float s2 = d0 * d0 + d1 * d1 + d2 * d2 + d3 * d3;
    #pragma unroll
    for (int off = 16; off; off >>= 1) s2 += __shfl_xor(s2, off, 32);
    float rstd = rsqrtf(s2 * (1.0f / 128.0f) + 1e-5f);
    const int row = g32 + 8 * j;
    a_l[(l32 * 4 + 0) * 32 + row] = d0 * rstd * qw.x;
    a_l[(l32 * 4 + 1) * 32 + row] = d1 * rstd * qw.y;
    a_l[(l32 * 4 + 2) * 32 + row] = d2 * rstd * qw.z;
    a_l[(l32 * 4 + 3) * 32 + row] = d3 * rstd * qw.w;
  }
  __syncthreads();

  const int tx = t & 31, ty = t >> 5;
  const int c0 = tx * 4, r0 = ty * 4;
  float acc[4][4];
  #pragma unroll
  for (int i = 0; i < 4; i++)
    #pragma unroll
    for (int j = 0; j < 4; j++) acc[i][j] = 0.0f;

  const int ob = t >> 1, kqb = (t & 1) * 16;
  for (int kt = 0; kt < 4; kt++) {
    const int k0 = kt * 32;
    {
      const float* bp = keys + (size_t)(cb + ob) * 128 + k0 + kqb;
      float4 b0 = *(const float4*)(bp);
      float4 b1 = *(const float4*)(bp + 4);
      float4 b2 = *(const float4*)(bp + 8);
      float4 b3 = *(const float4*)(bp + 12);
      b_lds[(kqb +  0) * 128 + ob] = b0.x;  b_lds[(kqb +  1) * 128 + ob] = b0.y;
      b_lds[(kqb +  2) * 128 + ob] = b0.z;  b_lds[(kqb +  3) * 128 + ob] = b0.w;
      b_lds[(kqb +  4) * 128 + ob] = b1.x;  b_lds[(kqb +  5) * 128 + ob] = b1.y;
      b_lds[(kqb +  6) * 128 + ob] = b1.z;  b_lds[(kqb +  7) * 128 + ob] = b1.w;
      b_lds[(kqb +  8) * 128 + ob] = b2.x;  b_lds[(kqb +  9) * 128 + ob] = b2.y;
      b_lds[(kqb + 10) * 128 + ob] = b2.z;  b_lds[(kqb + 11) * 128 + ob] = b2.w;
      b_lds[(kqb + 12) * 128 + ob] = b3.x;  b_lds[(kqb + 13) * 128 + ob] = b3.y;
      b_lds[(kqb + 14) * 128 + ob] = b3.z;  b_lds[(kqb + 15) * 128 + ob] = b3.w;
    }
    __syncthreads();
    #pragma unroll
    for (int k = 0; k < 32; k++) {
      float4 av = *(const float4*)(a_l + (k0 + k) * 32 + r0);
      float4 bv = *(const float4*)(b_lds + k * 128 + c0);
      float ar[4] = {av.x, av.y, av.z, av.w};
      float br[4] = {bv.x, bv.y, bv.z, bv.w};
      #pragma unroll
      for (int i = 0; i < 4; i++)
        #pragma unroll
        for (int j = 0; j < 4; j++)
          acc[i][j] = fmaf(ar[i], br[j], acc[i][j]);
    }
    __syncthreads();
  }
  #pragma unroll
  for (int i = 0; i < 4; i++) {
    float4 o4; o4.x = acc[i][0]; o4.y = acc[i][1]; o4.z = acc[i][2]; o4.w = acc[i][3];
    *(float4*)(C + (size_t)(rb + r0 + i) * 1024 + cb + c0) = o4;
  }
}

// ======================== ballot radix-select helpers =======================
__device__ inline unsigned f2ord(float f) {
  unsigned u = __float_as_uint(f);
  return (u & 0x80000000u) ? ~u : (u | 0x80000000u);
}
__device__ inline int lpc(unsigned long long m) {
  return __builtin_amdgcn_mbcnt_hi((unsigned)(m >> 32),
         __builtin_amdgcn_mbcnt_lo((unsigned)m, 0));
}

// ======= K3: fused tail (R7 form): select w/ early-exit, then gather ========
__global__ __launch_bounds__(256) void tail_kernel(const float* __restrict__ sc,
                                                   const float* __restrict__ misc,
                                                   const float* __restrict__ core,
                                                   const float* __restrict__ memories,
                                                   float* __restrict__ out)
{
  __shared__ __align__(16) float s_pl[1024];
  __shared__ int   tkbuf[4][32];
  __shared__ float mvals[4][32];
  __shared__ int   mcand[4][32];
  __shared__ int   s_idx[64];
  __shared__ float s_w[64];

  const int row = blockIdx.x;
  const int tid = threadIdx.x;
  ((float4*)s_pl)[tid] = ((const float4*)(sc + (size_t)row * 1024))[tid];
  __syncthreads();

  const int w = tid >> 6, lane = tid & 63;

  // ---- phase 1: wave w -> (head = w>>1, side = w&1), top-32 of 256 ----
  {
    const int h = w >> 1, side = w & 1;
    const float v0 = misc[side * 4 + h * 2 + 0];
    const float v1 = misc[side * 4 + h * 2 + 1];
    const float* p0 = s_pl + side * 512;
    const float* p1 = p0 + 256;
    const int mb = lane * 4;
    float4 a4 = *(const float4*)(p0 + mb);
    float4 b4 = *(const float4*)(p1 + mb);
    unsigned kk[4];
    kk[0] = f2ord(a4.x * v0 + b4.x * v1);
    kk[1] = f2ord(a4.y * v0 + b4.y * v1);
    kk[2] = f2ord(a4.z * v0 + b4.z * v1);
    kk[3] = f2ord(a4.w * v0 + b4.w * v1);
    unsigned tau = 0u;
    for (int b = 31; b >= 0; --b) {
      unsigned cand = tau | (1u << b);
      int cnt = 0;
      #pragma unroll
      for (int i = 0; i < 4; i++) cnt += __popcll(__ballot(kk[i] >= cand));
      if (cnt >= 32) {
        tau = cand;
        if (cnt == 32) break;   // exact top-32 set determined
      }
    }
    unsigned long long bG[4], bE[4];
    int cntG = 0, sbG = 0, sbE = 0;
    #pragma unroll
    for (int i = 0; i < 4; i++) {
      bG[i] = __ballot(kk[i] > tau);
      bE[i] = __ballot(kk[i] == tau);
      cntG += __popcll(bG[i]);
      sbG  += lpc(bG[i]);
      sbE  += lpc(bE[i]);
    }
    const int need = 32 - cntG;
    int runG = 0, runE = 0;
    #pragma unroll
    for (int i = 0; i < 4; i++) {
      if (kk[i] > tau)       { tkbuf[w][sbG + runG] = mb + i; runG++; }
      else if (kk[i] == tau) {
        int r = sbE + runE;
        if (r < need) tkbuf[w][cntG + r] = mb + i;
        runE++;
      }
    }
  }
  __syncthreads();

  // ---- phase 2: wave w -> (head = w>>1, half = w&1), top-32 of 512 ----
  {
    const int h = w >> 1, half = w & 1;
    const float c00 = core[h * 4 + 0], c01 = core[h * 4 + 1];
    const float c10 = core[h * 4 + 2], c11 = core[h * 4 + 3];
    const int i_glob = half * 16 + (lane >> 2);
    const int ri = tkbuf[h * 2 + 0][i_glob];
    const float fr0 = s_pl[ri], fr1 = s_pl[256 + ri];
    const float a0 = fr0 * c00 + fr1 * c10;
    const float a1 = fr0 * c01 + fr1 * c11;
    const int j0 = (lane & 3) * 8;
    float sv[8];
    unsigned kk[8];
    #pragma unroll
    for (int t2 = 0; t2 < 8; t2++) {
      int cj = tkbuf[h * 2 + 1][j0 + t2];
      sv[t2] = a0 * s_pl[512 + cj] + a1 * s_pl[768 + cj];
      kk[t2] = f2ord(sv[t2]);
    }
    unsigned tau = 0u;
    for (int b = 31; b >= 0; --b) {
      unsigned cand = tau | (1u << b);
      int cnt = 0;
      #pragma unroll
      for (int i = 0; i < 8; i++) cnt += __popcll(__ballot(kk[i] >= cand));
      if (cnt >= 32) {
        tau = cand;
        if (cnt == 32) break;   // exact top-32 set determined
      }
    }
    unsigned long long bG[8], bE[8];
    int cntG = 0, sbG = 0, sbE = 0;
    #pragma unroll
    for (int i = 0; i < 8; i++) {
      bG[i] = __ballot(kk[i] > tau);
      bE[i] = __ballot(kk[i] == tau);
      cntG += __popcll(bG[i]);
      sbG  += lpc(bG[i]);
      sbE  += lpc(bE[i]);
    }
    const int need = 32 - cntG;
    int runG = 0, runE = 0;
    #pragma unroll
    for (int i = 0; i < 8; i++) {
      int c = i_glob * 32 + j0 + i;
      if (kk[i] > tau) {
        mvals[w][sbG + runG] = sv[i]; mcand[w][sbG + runG] = c; runG++;
      } else if (kk[i] == tau) {
        int r = sbE + runE;
        if (r < need) { mvals[w][cntG + r] = sv[i]; mcand[w][cntG + r] = c; }
        runE++;
      }
    }
  }
  __syncthreads();

  // ---- merge two half-lists per head by rank-count ----
  if (w < 2) {
    const int h = w;
    const int half2 = lane >> 5, k = lane & 31;
    const float v = mvals[h * 2 + half2][k];
    const int   c = mcand[h * 2 + half2][k];
    int cnt = 0;
    #pragma unroll 8
    for (int j = 0; j < 64; j++) {
      float u = mvals[h * 2 + (j >> 5)][j & 31];
      int  uc = mcand[h * 2 + (j >> 5)][j & 31];
      cnt += (u > v || (u == v && uc < c)) ? 1 : 0;
    }
    if (cnt < 32) {
      int ii = c >> 5, jj = c & 31;
      s_idx[h * 32 + cnt] = tkbuf[h * 2][ii] * 256 + tkbuf[h * 2 + 1][jj];
      s_w[h * 32 + cnt]   = 1.0f / (1.0f + expf(-v));
    }
  }
  __syncthreads();

  // ---- weighted gather-sum: double-buffered batches of 8 loads ----
  const int h2 = tid >> 7;
  const int d4 = tid & 127;
  const int base = h2 * 32;
  const float* mb = memories + d4 * 4;
  float ax = 0.f, ay = 0.f, az = 0.f, aw = 0.f;
  float4 va[8], vb[8];
  float  wa[8], wb[8];
  #pragma unroll
  for (int i = 0; i < 8; i++) {
    int mi = s_idx[base + i]; wa[i] = s_w[base + i];
    va[i] = *(const float4*)(mb + (size_t)mi * 512);
  }
  #pragma unroll
  for (int i = 0; i < 8; i++) {
    int mi = s_idx[base + 8 + i]; wb[i] = s_w[base + 8 + i];
    vb[i] = *(const float4*)(mb + (size_t)mi * 512);
  }
  #pragma unroll
  for (int i = 0; i < 8; i++) {
    ax = fmaf(wa[i], va[i].x, ax); ay = fmaf(wa[i], va[i].y, ay);
    az = fmaf(wa[i], va[i].z, az); aw = fmaf(wa[i], va[i].w, aw);
  }
  #pragma unroll
  for (int i = 0; i < 8; i++) {
    int mi = s_idx[base + 16 + i]; wa[i] = s_w[base + 16 + i];
    va[i] = *(const float4*)(mb + (size_t)mi * 512);
  }
  #pragma unroll
  for (int i = 0; i < 8; i++) {
    ax = fmaf(wb[i], vb[i].x, ax); ay = fmaf(wb[i], vb[i].y, ay);
    az = fmaf(wb[i], vb[i].z, az); aw = fmaf(wb[i], vb[i].w, aw);
  }
  #pragma unroll
  for (int i = 0; i < 8; i++) {
    int mi = s_idx[base + 24 + i]; wb[i] = s_w[base + 24 + i];
    vb[i] = *(const float4*)(mb + (size_t)mi * 512);
  }
  #pragma unroll
  for (int i = 0; i < 8; i++) {
    ax = fmaf(wa[i], va[i].x, ax); ay = fmaf(wa[i], va[i].y, ay);
    az = fmaf(wa[i], va[i].z, az); aw = fmaf(wa[i], va[i].w, aw);
  }
  #pragma unroll
  for (int i = 0; i < 8; i++) {
    ax = fmaf(wb[i], vb[i].x, ax); ay = fmaf(wb[i], vb[i].y, ay);
    az = fmaf(wb[i], vb[i].z, az); aw = fmaf(wb[i], vb[i].w, aw);
  }
  float4 o4; o4.x = ax; o4.y = ay; o4.z = az; o4.w = aw;
  ((float4*)out)[(size_t)row * 256 + tid] = o4;
}

// ============================== launcher ====================================
extern "C" void kernel_launch(void* const* d_in, const int* in_sizes, int n_in,
                              void* d_out, int out_size, void* d_ws, size_t ws_size,
                              hipStream_t stream) {
  const float* tokens = (const float*)d_in[0];
  const float* rms_w  = (const float*)d_in[1];
  const float* conv_w = (const float*)d_in[2];
  const float* conv_b = (const float*)d_in[3];
  const float* wq     = (const float*)d_in[4];
  const float* qln_w  = (const float*)d_in[5];
  const float* keys   = (const float*)d_in[6];
  const float* core   = (const float*)d_in[7];
  const float* mems   = (const float*)d_in[8];
  float* out = (float*)d_out;
  float* ws  = (float*)d_ws;

  // workspace layout (floats)
  float* misc  = ws;                       // 8
  float* invs  = ws + 1024;                // 2048
  float* qpart = ws + 4096;                // KSPLIT * 2048*128 = 2,097,152
  float* sc    = qpart + 2097152;          // 2048*1024

  rms_kernel     <<<ROWS / 8, 256, 0, stream>>>(tokens, core, invs, misc,
                                                out + 2097152);
  // ATTRIBUTION: convgemm1 x3 and gemm2ln x3 (idempotent rewrites).
  // (t_cg1 + t_g2ln) = (dur - 273.7) / 2.
  convgemm1_kernel<<<dim3(64, KSPLIT), 256, 0, stream>>>(tokens, invs, rms_w,
                                                         conv_w, conv_b, wq, qpart);
  convgemm1_kernel<<<dim3(64, KSPLIT), 256, 0, stream>>>(tokens, invs, rms_w,
                                                         conv_w, conv_b, wq, qpart);
  convgemm1_kernel<<<dim3(64, KSPLIT), 256, 0, stream>>>(tokens, invs, rms_w,
                                                         conv_w, conv_b, wq, qpart);
  gemm2ln_kernel <<<dim3(64, 8), 256, 0, stream>>>(qpart, qln_w, keys, sc);
  gemm2ln_kernel <<<dim3(64, 8), 256, 0, stream>>>(qpart, qln_w, keys, sc);
  gemm2ln_kernel <<<dim3(64, 8), 256, 0, stream>>>(qpart, qln_w, keys, sc);
  tail_kernel    <<<ROWS, 256, 0, stream>>>(sc, misc, core, mems, out);
}

// Round 10
// 295.408 us; speedup vs baseline: 1.1261x; 1.1261x over previous
//
#include <hip/hip_runtime.h>
#include <math.h>

// ---------------------------------------------------------------------------
// UltraMem forward, MI355X. B=2 N=1024 DIM=1024 DQK=128 NUM_KEYS=256 TOPK=32
// RANK=2 HEADS=2 DV=512 KCONV=5.
// R10: tail split by (token, head): 4096 blocks (2/token), halving per-block
// select work and doubling independent select/gather chains per CU (R8 lesson:
// TLP, not intra-block state). Gather = float2/thread, preserving the exact
// sequential i=0..31 accumulation order (bitwise-identical output).
// Front-end = R7 (rms / convgemm1 32-row / gemm2ln), single launches.
// R9 attribution: cg1+g2ln+2gaps = 29.5us total -> not worth further rounds.
// ---------------------------------------------------------------------------

#define ROWS 2048            // B*N
#define KSPLIT 8             // gemm1 K partitions

// ======================= 2x2 SVD (LAPACK dgesdd replica) ====================
__device__ inline double dsgn(double x, double y) { return (y >= 0.0) ? fabs(x) : -fabs(x); }

__device__ void dlasv2_dev(double f, double g, double h,
                           double& ssmin, double& ssmax,
                           double& snr, double& csr, double& snl, double& csl)
{
  const double EPSD = 2.2204460492503131e-16;
  double ft = f, fa = fabs(f), ht = h, ha = fabs(h);
  int pmax = 1;
  bool swp = (ha > fa);
  if (swp) { pmax = 3; double tp = ft; ft = ht; ht = tp; tp = fa; fa = ha; ha = tp; }
  double gt = g, ga = fabs(gt);
  double clt = 0.0, crt = 0.0, slt = 0.0, srt = 0.0;
  if (ga == 0.0) {
    ssmin = ha; ssmax = fa; clt = 1.0; crt = 1.0; slt = 0.0; srt = 0.0;
  } else {
    bool gasmal = true;
    if (ga > fa) {
      pmax = 2;
      if ((fa / ga) < EPSD) {
        gasmal = false;
        ssmax = ga;
        if (ha > 1.0) ssmin = fa / (ga / ha); else ssmin = (fa / ga) * ha;
        clt = 1.0; slt = ht / gt; srt = 1.0; crt = ft / gt;
      }
    }
    if (gasmal) {
      double dd = fa - ha, l;
      if (dd == fa) l = 1.0; else l = dd / fa;
      double m  = gt / ft;
      double t  = 2.0 - l;
      double mm = m * m, tt = t * t;
      double s  = sqrt(tt + mm);
      double r  = (l == 0.0) ? fabs(m) : sqrt(l * l + mm);
      double a  = 0.5 * (s + r);
      ssmin = ha / a;
      ssmax = fa * a;
      if (mm == 0.0) {
        if (l == 0.0) t = dsgn(2.0, ft) * dsgn(1.0, gt);
        else          t = gt / dsgn(dd, ft) + m / t;
      } else {
        t = (m / (s + t) + m / (r + l)) * (1.0 + a);
      }
      double ll = sqrt(t * t + 4.0);
      crt = 2.0 / ll;
      srt = t / ll;
      clt = (crt + srt * m) / a;
      slt = (ht / ft) * srt / a;
    }
  }
  if (swp) { csl = srt; snl = crt; csr = slt; snr = clt; }
  else     { csl = clt; snl = slt; csr = crt; snr = srt; }
  double tsign = 1.0;
  if (pmax == 1) tsign = dsgn(1.0, csr) * dsgn(1.0, csl) * dsgn(1.0, f);
  if (pmax == 2) tsign = dsgn(1.0, snr) * dsgn(1.0, csl) * dsgn(1.0, g);
  if (pmax == 3) tsign = dsgn(1.0, snr) * dsgn(1.0, snl) * dsgn(1.0, h);
  ssmax = dsgn(ssmax, tsign);
  ssmin = dsgn(ssmin, tsign * dsgn(1.0, f) * dsgn(1.0, h));
}

__device__ void do_svd(const float* __restrict__ core, float* __restrict__ misc,
                       float* __restrict__ aux_out)
{
  double aux = 0.0;
  for (int hh = 0; hh < 2; hh++) {
    double a = (double)core[hh * 4 + 0];
    double b = (double)core[hh * 4 + 1];
    double c = (double)core[hh * 4 + 2];
    double d = (double)core[hh * 4 + 3];
    double tau = 0.0, v2 = 0.0, d1, e, d2;
    if (c != 0.0) {
      double nrm  = sqrt(a * a + c * c);
      double beta = (a >= 0.0) ? -nrm : nrm;
      tau = (beta - a) / beta;
      v2  = c / (a - beta);
      double wsum = b + v2 * d;
      d1 = beta;
      e  = b - tau * wsum;
      d2 = d - tau * v2 * wsum;
    } else { d1 = a; e = b; d2 = d; }
    double ssmin, ssmax, snr, csr, snl, csl;
    dlasv2_dev(d1, e, d2, ssmin, ssmax, snr, csr, snl, csl);
    double t0 = csl + v2 * snl;
    double u0 = csl - tau * t0;
    double u1 = snl - tau * v2 * t0;
    double sg = (ssmax < 0.0) ? -1.0 : 1.0;
    misc[hh * 2 + 0]     = (float)u0;
    misc[hh * 2 + 1]     = (float)u1;
    misc[4 + hh * 2 + 0] = (float)(sg * csr);
    misc[4 + hh * 2 + 1] = (float)(sg * snr);
    double s2 = fabs(ssmin);
    double rl = s2 - 0.15; if (rl < 0.0) rl = 0.0;
    aux += rl * rl;
  }
  aux_out[0] = (float)(aux * 0.1);
}

// ================== K0: per-row RMS inv_s (8 rows/block) + SVD ==============
__global__ __launch_bounds__(256) void rms_kernel(const float* __restrict__ tokens,
                                                  const float* __restrict__ core,
                                                  float* __restrict__ inv_sg,
                                                  float* __restrict__ misc,
                                                  float* __restrict__ aux_out)
{
  __shared__ float red[8][4];
  const int t    = threadIdx.x;
  const int row0 = blockIdx.x * 8;
  const int c0   = t * 4;
  float sq[8];
  #pragma unroll
  for (int s = 0; s < 8; s++) {
    float4 v = *(const float4*)(tokens + (size_t)(row0 + s) * 1024 + c0);
    sq[s] = v.x * v.x + v.y * v.y + v.z * v.z + v.w * v.w;
  }
  #pragma unroll
  for (int off = 32; off; off >>= 1) {
    #pragma unroll
    for (int s = 0; s < 8; s++) sq[s] += __shfl_down(sq[s], off, 64);
  }
  const int lane = t & 63, w = t >> 6;
  if (lane == 0) {
    #pragma unroll
    for (int s = 0; s < 8; s++) red[s][w] = sq[s];
  }
  __syncthreads();
  if (t < 8)
    inv_sg[row0 + t] = rsqrtf((red[t][0] + red[t][1] + red[t][2] + red[t][3])
                              * (1.0f / 1024.0f) + 1.1920929e-07f);
  if (blockIdx.x == 0 && t == 0) do_svd(core, misc, aux_out);
}

// ===== K1: fused conv + gemm1, 32-row tiles. grid (64, KSPLIT). =============
__global__ __launch_bounds__(256) void convgemm1_kernel(
    const float* __restrict__ tokens, const float* __restrict__ inv_sg,
    const float* __restrict__ rms_w,  const float* __restrict__ conv_w,
    const float* __restrict__ conv_b, const float* __restrict__ wq,
    float* __restrict__ qpart)
{
  __shared__ float xh[36 * 33];                    // [srow][c], stride 33
  __shared__ __align__(16) float a_lds[32 * 32];   // [k][row]
  __shared__ __align__(16) float b_lds[32 * 128];  // [k][col]
  __shared__ float inv_l[36];
  const int t  = threadIdx.x;
  const int rb = blockIdx.x * 32;
  const int kb = blockIdx.y * 128;
  const int n0 = rb & 1023;          // 32-aligned => whole block same batch

  if (t < 36) inv_l[t] = (n0 - 4 + t >= 0) ? inv_sg[rb - 4 + t] : 0.0f;

  const int tx = t & 31, ty = t >> 5;
  const int c0g = tx * 4, r0 = ty * 4;
  float acc[4][4];
  #pragma unroll
  for (int i = 0; i < 4; i++)
    #pragma unroll
    for (int j = 0; j < 4; j++) acc[i][j] = 0.0f;

  const int ob = t >> 1, kqb = (t & 1) * 16;   // wq staging map
  const int cr = t & 31;                       // conv: row
  const int ch = (t >> 5) * 4;                 // conv: col base (4 cols/thread)

  for (int kt = 0; kt < 4; kt++) {
    const int k0 = kb + kt * 32;
    __syncthreads();                 // prev GEMM done before overwriting LDS
    #pragma unroll
    for (int it = 0; it < 2; it++) {
      int idx  = it * 256 + t;
      int srow = idx >> 3, f4 = (idx & 7) * 4;
      if (srow < 36) {
        float4 v = make_float4(0.f, 0.f, 0.f, 0.f);
        if (n0 - 4 + srow >= 0)
          v = *(const float4*)(tokens + (size_t)(rb - 4 + srow) * 1024 + k0 + f4);
        float iv = inv_l[srow];
        xh[srow * 33 + f4 + 0] = v.x * iv;
        xh[srow * 33 + f4 + 1] = v.y * iv;
        xh[srow * 33 + f4 + 2] = v.z * iv;
        xh[srow * 33 + f4 + 3] = v.w * iv;
      }
    }
    {
      const float* bp = wq + (size_t)ob * 1024 + k0 + kqb;
      float4 b0 = *(const float4*)(bp);
      float4 b1 = *(const float4*)(bp + 4);
      float4 b2 = *(const float4*)(bp + 8);
      float4 b3 = *(const float4*)(bp + 12);
      b_lds[(kqb +  0) * 128 + ob] = b0.x;  b_lds[(kqb +  1) * 128 + ob] = b0.y;
      b_lds[(kqb +  2) * 128 + ob] = b0.z;  b_lds[(kqb +  3) * 128 + ob] = b0.w;
      b_lds[(kqb +  4) * 128 + ob] = b1.x;  b_lds[(kqb +  5) * 128 + ob] = b1.y;
      b_lds[(kqb +  6) * 128 + ob] = b1.z;  b_lds[(kqb +  7) * 128 + ob] = b1.w;
      b_lds[(kqb +  8) * 128 + ob] = b2.x;  b_lds[(kqb +  9) * 128 + ob] = b2.y;
      b_lds[(kqb + 10) * 128 + ob] = b2.z;  b_lds[(kqb + 11) * 128 + ob] = b2.w;
      b_lds[(kqb + 12) * 128 + ob] = b3.x;  b_lds[(kqb + 13) * 128 + ob] = b3.y;
      b_lds[(kqb + 14) * 128 + ob] = b3.z;  b_lds[(kqb + 15) * 128 + ob] = b3.w;
    }
    __syncthreads();
    #pragma unroll
    for (int i = 0; i < 4; i++) {
      const int c = ch + i;
      const float* cw = conv_w + (size_t)(k0 + c) * 5;
      float a = xh[(cr + 0) * 33 + c] * cw[0]
              + xh[(cr + 1) * 33 + c] * cw[1]
              + xh[(cr + 2) * 33 + c] * cw[2]
              + xh[(cr + 3) * 33 + c] * cw[3]
              + xh[(cr + 4) * 33 + c] * cw[4];
      a_lds[c * 32 + cr] = a * rms_w[k0 + c] + conv_b[k0 + c];
    }
    __syncthreads();
    #pragma unroll
    for (int k = 0; k < 32; k++) {
      float4 av = *(const float4*)(a_lds + k * 32 + r0);
      float4 bv = *(const float4*)(b_lds + k * 128 + c0g);
      float ar[4] = {av.x, av.y, av.z, av.w};
      float br[4] = {bv.x, bv.y, bv.z, bv.w};
      #pragma unroll
      for (int i = 0; i < 4; i++)
        #pragma unroll
        for (int j = 0; j < 4; j++)
          acc[i][j] = fmaf(ar[i], br[j], acc[i][j]);
    }
  }
  float* C = qpart + (size_t)blockIdx.y * (ROWS * 128);
  #pragma unroll
  for (int i = 0; i < 4; i++) {
    float4 o4; o4.x = acc[i][0]; o4.y = acc[i][1]; o4.z = acc[i][2]; o4.w = acc[i][3];
    *(float4*)(C + (size_t)(rb + r0 + i) * 128 + c0g) = o4;
  }
}

// ========== K2: gemm2 with fused plane-reduce + LayerNorm (A side) =========
__global__ __launch_bounds__(256) void gemm2ln_kernel(const float* __restrict__ qpart,
                                                      const float* __restrict__ qln_w,
                                                      const float* __restrict__ keys,
                                                      float* __restrict__ C)
{
  __shared__ __align__(16) float a_l[128 * 32];     // [k][row], normalized
  __shared__ __align__(16) float b_lds[32 * 128];   // [k][col]
  const int t  = threadIdx.x;
  const int rb = blockIdx.x * 32;
  const int cb = blockIdx.y * 128;

  const int l32 = t & 31;          // k cols l32*4 .. +3
  const int g32 = t >> 5;          // rows g32 + 8*j
  float vs[4][4];
  #pragma unroll
  for (int j = 0; j < 4; j++) { vs[j][0]=0.f; vs[j][1]=0.f; vs[j][2]=0.f; vs[j][3]=0.f; }
  #pragma unroll
  for (int g = 0; g < KSPLIT; g++) {
    const float* pg = qpart + (size_t)g * (ROWS * 128) + (size_t)rb * 128 + l32 * 4;
    #pragma unroll
    for (int j = 0; j < 4; j++) {
      float4 v = *(const float4*)(pg + (g32 + 8 * j) * 128);
      vs[j][0] += v.x; vs[j][1] += v.y; vs[j][2] += v.z; vs[j][3] += v.w;
    }
  }
  float4 qw = *(const float4*)(qln_w + l32 * 4);
  #pragma unroll
  for (int j = 0; j < 4; j++) {
    float s1 = vs[j][0] + vs[j][1] + vs[j][2] + vs[j][3];
    #pragma unroll
    for (int off = 16; off; off >>= 1) s1 += __shfl_xor(s1, off, 32);
    float mu = s1 * (1.0f / 128.0f);
    float d0 = vs[j][0] - mu, d1 = vs[j][1] - mu, d2 = vs[j][2] - mu, d3 = vs[j][3] - mu;
    float s2 = d0 * d0 + d1 * d1 + d2 * d2 + d3 * d3;
    #pragma unroll
    for (int off = 16; off; off >>= 1) s2 += __shfl_xor(s2, off, 32);
    float rstd = rsqrtf(s2 * (1.0f / 128.0f) + 1e-5f);
    const int row = g32 + 8 * j;
    a_l[(l32 * 4 + 0) * 32 + row] = d0 * rstd * qw.x;
    a_l[(l32 * 4 + 1) * 32 + row] = d1 * rstd * qw.y;
    a_l[(l32 * 4 + 2) * 32 + row] = d2 * rstd * qw.z;
    a_l[(l32 * 4 + 3) * 32 + row] = d3 * rstd * qw.w;
  }
  __syncthreads();

  const int tx = t & 31, ty = t >> 5;
  const int c0 = tx * 4, r0 = ty * 4;
  float acc[4][4];
  #pragma unroll
  for (int i = 0; i < 4; i++)
    #pragma unroll
    for (int j = 0; j < 4; j++) acc[i][j] = 0.0f;

  const int ob = t >> 1, kqb = (t & 1) * 16;
  for (int kt = 0; kt < 4; kt++) {
    const int k0 = kt * 32;
    {
      const float* bp = keys + (size_t)(cb + ob) * 128 + k0 + kqb;
      float4 b0 = *(const float4*)(bp);
      float4 b1 = *(const float4*)(bp + 4);
      float4 b2 = *(const float4*)(bp + 8);
      float4 b3 = *(const float4*)(bp + 12);
      b_lds[(kqb +  0) * 128 + ob] = b0.x;  b_lds[(kqb +  1) * 128 + ob] = b0.y;
      b_lds[(kqb +  2) * 128 + ob] = b0.z;  b_lds[(kqb +  3) * 128 + ob] = b0.w;
      b_lds[(kqb +  4) * 128 + ob] = b1.x;  b_lds[(kqb +  5) * 128 + ob] = b1.y;
      b_lds[(kqb +  6) * 128 + ob] = b1.z;  b_lds[(kqb +  7) * 128 + ob] = b1.w;
      b_lds[(kqb +  8) * 128 + ob] = b2.x;  b_lds[(kqb +  9) * 128 + ob] = b2.y;
      b_lds[(kqb + 10) * 128 + ob] = b2.z;  b_lds[(kqb + 11) * 128 + ob] = b2.w;
      b_lds[(kqb + 12) * 128 + ob] = b3.x;  b_lds[(kqb + 13) * 128 + ob] = b3.y;
      b_lds[(kqb + 14) * 128 + ob] = b3.z;  b_lds[(kqb + 15) * 128 + ob] = b3.w;
    }
    __syncthreads();
    #pragma unroll
    for (int k = 0; k < 32; k++) {
      float4 av = *(const float4*)(a_l + (k0 + k) * 32 + r0);
      float4 bv = *(const float4*)(b_lds + k * 128 + c0);
      float ar[4] = {av.x, av.y, av.z, av.w};
      float br[4] = {bv.x, bv.y, bv.z, bv.w};
      #pragma unroll
      for (int i = 0; i < 4; i++)
        #pragma unroll
        for (int j = 0; j < 4; j++)
          acc[i][j] = fmaf(ar[i], br[j], acc[i][j]);
    }
    __syncthreads();
  }
  #pragma unroll
  for (int i = 0; i < 4; i++) {
    float4 o4; o4.x = acc[i][0]; o4.y = acc[i][1]; o4.z = acc[i][2]; o4.w = acc[i][3];
    *(float4*)(C + (size_t)(rb + r0 + i) * 1024 + cb + c0) = o4;
  }
}

// ======================== ballot radix-select helpers =======================
__device__ inline unsigned f2ord(float f) {
  unsigned u = __float_as_uint(f);
  return (u & 0x80000000u) ? ~u : (u | 0x80000000u);
}
__device__ inline int lpc(unsigned long long m) {
  return __builtin_amdgcn_mbcnt_hi((unsigned)(m >> 32),
         __builtin_amdgcn_mbcnt_lo((unsigned)m, 0));
}

// ====== K3: tail, one block per (token, head). 4096 blocks. =================
// Waves 0,1 do select (identical arithmetic to the 4-wave version, restricted
// to head h = blockIdx.x & 1); waves 2,3 idle through select barriers and
// join for the gather. Gather: 256 threads x float2, i-order 0..31 sequential
// per element -> bitwise-identical accumulation to R7.
__global__ __launch_bounds__(256) void tail_kernel(const float* __restrict__ sc,
                                                   const float* __restrict__ misc,
                                                   const float* __restrict__ core,
                                                   const float* __restrict__ memories,
                                                   float* __restrict__ out)
{
  __shared__ __align__(16) float s_pl[1024];
  __shared__ int   tkbuf[2][32];     // [side][k]
  __shared__ float mvals[2][32];     // [half][k]
  __shared__ int   mcand[2][32];
  __shared__ int   s_idx[32];
  __shared__ float s_w[32];

  const int bid = blockIdx.x;
  const int row = bid >> 1, h = bid & 1;
  const int tid = threadIdx.x;
  ((float4*)s_pl)[tid] = ((const float4*)(sc + (size_t)row * 1024))[tid];
  __syncthreads();

  const int w = tid >> 6, lane = tid & 63;

  // ---- phase 1: wave w in {0,1} -> side w, top-32 of 256 (this head) ----
  if (w < 2) {
    const int side = w;
    const float v0 = misc[side * 4 + h * 2 + 0];
    const float v1 = misc[side * 4 + h * 2 + 1];
    const float* p0 = s_pl + side * 512;
    const float* p1 = p0 + 256;
    const int mb = lane * 4;
    float4 a4 = *(const float4*)(p0 + mb);
    float4 b4 = *(const float4*)(p1 + mb);
    unsigned kk[4];
    kk[0] = f2ord(a4.x * v0 + b4.x * v1);
    kk[1] = f2ord(a4.y * v0 + b4.y * v1);
    kk[2] = f2ord(a4.z * v0 + b4.z * v1);
    kk[3] = f2ord(a4.w * v0 + b4.w * v1);
    unsigned tau = 0u;
    for (int b = 31; b >= 0; --b) {
      unsigned cand = tau | (1u << b);
      int cnt = 0;
      #pragma unroll
      for (int i = 0; i < 4; i++) cnt += __popcll(__ballot(kk[i] >= cand));
      if (cnt >= 32) {
        tau = cand;
        if (cnt == 32) break;   // exact top-32 set determined
      }
    }
    unsigned long long bG[4], bE[4];
    int cntG = 0, sbG = 0, sbE = 0;
    #pragma unroll
    for (int i = 0; i < 4; i++) {
      bG[i] = __ballot(kk[i] > tau);
      bE[i] = __ballot(kk[i] == tau);
      cntG += __popcll(bG[i]);
      sbG  += lpc(bG[i]);
      sbE  += lpc(bE[i]);
    }
    const int need = 32 - cntG;
    int runG = 0, runE = 0;
    #pragma unroll
    for (int i = 0; i < 4; i++) {
      if (kk[i] > tau)       { tkbuf[side][sbG + runG] = mb + i; runG++; }
      else if (kk[i] == tau) {
        int r = sbE + runE;
        if (r < need) tkbuf[side][cntG + r] = mb + i;
        runE++;
      }
    }
  }
  __syncthreads();

  // ---- phase 2: wave w in {0,1} -> half w, top-32 of 512 (this head) ----
  if (w < 2) {
    const int half = w;
    const float c00 = core[h * 4 + 0], c01 = core[h * 4 + 1];
    const float c10 = core[h * 4 + 2], c11 = core[h * 4 + 3];
    const int i_glob = half * 16 + (lane >> 2);
    const int ri = tkbuf[0][i_glob];
    const float fr0 = s_pl[ri], fr1 = s_pl[256 + ri];
    const float a0 = fr0 * c00 + fr1 * c10;
    const float a1 = fr0 * c01 + fr1 * c11;
    const int j0 = (lane & 3) * 8;
    float sv[8];
    unsigned kk[8];
    #pragma unroll
    for (int t2 = 0; t2 < 8; t2++) {
      int cj = tkbuf[1][j0 + t2];
      sv[t2] = a0 * s_pl[512 + cj] + a1 * s_pl[768 + cj];
      kk[t2] = f2ord(sv[t2]);
    }
    unsigned tau = 0u;
    for (int b = 31; b >= 0; --b) {
      unsigned cand = tau | (1u << b);
      int cnt = 0;
      #pragma unroll
      for (int i = 0; i < 8; i++) cnt += __popcll(__ballot(kk[i] >= cand));
      if (cnt >= 32) {
        tau = cand;
        if (cnt == 32) break;   // exact top-32 set determined
      }
    }
    unsigned long long bG[8], bE[8];
    int cntG = 0, sbG = 0, sbE = 0;
    #pragma unroll
    for (int i = 0; i < 8; i++) {
      bG[i] = __ballot(kk[i] > tau);
      bE[i] = __ballot(kk[i] == tau);
      cntG += __popcll(bG[i]);
      sbG  += lpc(bG[i]);
      sbE  += lpc(bE[i]);
    }
    const int need = 32 - cntG;
    int runG = 0, runE = 0;
    #pragma unroll
    for (int i = 0; i < 8; i++) {
      int c = i_glob * 32 + j0 + i;
      if (kk[i] > tau) {
        mvals[half][sbG + runG] = sv[i]; mcand[half][sbG + runG] = c; runG++;
      } else if (kk[i] == tau) {
        int r = sbE + runE;
        if (r < need) { mvals[half][cntG + r] = sv[i]; mcand[half][cntG + r] = c; }
        runE++;
      }
    }
  }
  __syncthreads();

  // ---- merge two half-lists by rank-count (wave 0, 64 lanes) ----
  if (w == 0) {
    const int half2 = lane >> 5, k = lane & 31;
    const float v = mvals[half2][k];
    const int   c = mcand[half2][k];
    int cnt = 0;
    #pragma unroll 8
    for (int j = 0; j < 64; j++) {
      float u = mvals[j >> 5][j & 31];
      int  uc = mcand[j >> 5][j & 31];
      cnt += (u > v || (u == v && uc < c)) ? 1 : 0;
    }
    if (cnt < 32) {
      int ii = c >> 5, jj = c & 31;
      s_idx[cnt] = tkbuf[0][ii] * 256 + tkbuf[1][jj];
      s_w[cnt]   = 1.0f / (1.0f + expf(-v));
    }
  }
  __syncthreads();

  // ---- weighted gather-sum: float2/thread, batches of 8 in flight ----
  const float* mp = memories + tid * 2;
  float ax = 0.f, ay = 0.f;
  float2 va[8], vb[8];
  float  wa[8], wb[8];
  #pragma unroll
  for (int i = 0; i < 8; i++) {
    int mi = s_idx[i]; wa[i] = s_w[i];
    va[i] = *(const float2*)(mp + (size_t)mi * 512);
  }
  #pragma unroll
  for (int i = 0; i < 8; i++) {
    int mi = s_idx[8 + i]; wb[i] = s_w[8 + i];
    vb[i] = *(const float2*)(mp + (size_t)mi * 512);
  }
  #pragma unroll
  for (int i = 0; i < 8; i++) {
    ax = fmaf(wa[i], va[i].x, ax); ay = fmaf(wa[i], va[i].y, ay);
  }
  #pragma unroll
  for (int i = 0; i < 8; i++) {
    int mi = s_idx[16 + i]; wa[i] = s_w[16 + i];
    va[i] = *(const float2*)(mp + (size_t)mi * 512);
  }
  #pragma unroll
  for (int i = 0; i < 8; i++) {
    ax = fmaf(wb[i], vb[i].x, ax); ay = fmaf(wb[i], vb[i].y, ay);
  }
  #pragma unroll
  for (int i = 0; i < 8; i++) {
    int mi = s_idx[24 + i]; wb[i] = s_w[24 + i];
    vb[i] = *(const float2*)(mp + (size_t)mi * 512);
  }
  #pragma unroll
  for (int i = 0; i < 8; i++) {
    ax = fmaf(wa[i], va[i].x, ax); ay = fmaf(wa[i], va[i].y, ay);
  }
  #pragma unroll
  for (int i = 0; i < 8; i++) {
    ax = fmaf(wb[i], vb[i].x, ax); ay = fmaf(wb[i], vb[i].y, ay);
  }
  float2 o2; o2.x = ax; o2.y = ay;
  *(float2*)(out + (size_t)row * 1024 + h * 512 + tid * 2) = o2;
}

// ============================== launcher ====================================
extern "C" void kernel_launch(void* const* d_in, const int* in_sizes, int n_in,
                              void* d_out, int out_size, void* d_ws, size_t ws_size,
                              hipStream_t stream) {
  const float* tokens = (const float*)d_in[0];
  const float* rms_w  = (const float*)d_in[1];
  const float* conv_w = (const float*)d_in[2];
  const float* conv_b = (const float*)d_in[3];
  const float* wq     = (const float*)d_in[4];
  const float* qln_w  = (const float*)d_in[5];
  const float* keys   = (const float*)d_in[6];
  const float* core   = (const float*)d_in[7];
  const float* mems   = (const float*)d_in[8];
  float* out = (float*)d_out;
  float* ws  = (float*)d_ws;

  // workspace layout (floats)
  float* misc  = ws;                       // 8
  float* invs  = ws + 1024;                // 2048
  float* qpart = ws + 4096;                // KSPLIT * 2048*128 = 2,097,152
  float* sc    = qpart + 2097152;          // 2048*1024

  rms_kernel     <<<ROWS / 8, 256, 0, stream>>>(tokens, core, invs, misc,
                                                out + 2097152);
  convgemm1_kernel<<<dim3(64, KSPLIT), 256, 0, stream>>>(tokens, invs, rms_w,
                                                         conv_w, conv_b, wq, qpart);
  gemm2ln_kernel <<<dim3(64, 8), 256, 0, stream>>>(qpart, qln_w, keys, sc);
  tail_kernel    <<<ROWS * 2, 256, 0, stream>>>(sc, misc, core, mems, out);
}

// Round 11
// 287.200 us; speedup vs baseline: 1.1583x; 1.0286x over previous
//
#include <hip/hip_runtime.h>
#include <math.h>

// ---------------------------------------------------------------------------
// UltraMem forward, MI355X. B=2 N=1024 DIM=1024 DQK=128 NUM_KEYS=256 TOPK=32
// RANK=2 HEADS=2 DV=512 KCONV=5.
// R11: 3 kernels. rms folded into convgemm1 (per-block inv_s for its 36 rows,
// bitwise-identical reduction order to the old rms_kernel; SVD in block 0,0).
// gemm2ln unchanged. tail = R7 exact (R8/R10 restructures both regressed:
// R7's 2048-block float4-gather shape is the local optimum).
// ---------------------------------------------------------------------------

#define ROWS 2048            // B*N
#define KSPLIT 8             // gemm1 K partitions

// ======================= 2x2 SVD (LAPACK dgesdd replica) ====================
__device__ inline double dsgn(double x, double y) { return (y >= 0.0) ? fabs(x) : -fabs(x); }

__device__ void dlasv2_dev(double f, double g, double h,
                           double& ssmin, double& ssmax,
                           double& snr, double& csr, double& snl, double& csl)
{
  const double EPSD = 2.2204460492503131e-16;
  double ft = f, fa = fabs(f), ht = h, ha = fabs(h);
  int pmax = 1;
  bool swp = (ha > fa);
  if (swp) { pmax = 3; double tp = ft; ft = ht; ht = tp; tp = fa; fa = ha; ha = tp; }
  double gt = g, ga = fabs(gt);
  double clt = 0.0, crt = 0.0, slt = 0.0, srt = 0.0;
  if (ga == 0.0) {
    ssmin = ha; ssmax = fa; clt = 1.0; crt = 1.0; slt = 0.0; srt = 0.0;
  } else {
    bool gasmal = true;
    if (ga > fa) {
      pmax = 2;
      if ((fa / ga) < EPSD) {
        gasmal = false;
        ssmax = ga;
        if (ha > 1.0) ssmin = fa / (ga / ha); else ssmin = (fa / ga) * ha;
        clt = 1.0; slt = ht / gt; srt = 1.0; crt = ft / gt;
      }
    }
    if (gasmal) {
      double dd = fa - ha, l;
      if (dd == fa) l = 1.0; else l = dd / fa;
      double m  = gt / ft;
      double t  = 2.0 - l;
      double mm = m * m, tt = t * t;
      double s  = sqrt(tt + mm);
      double r  = (l == 0.0) ? fabs(m) : sqrt(l * l + mm);
      double a  = 0.5 * (s + r);
      ssmin = ha / a;
      ssmax = fa * a;
      if (mm == 0.0) {
        if (l == 0.0) t = dsgn(2.0, ft) * dsgn(1.0, gt);
        else          t = gt / dsgn(dd, ft) + m / t;
      } else {
        t = (m / (s + t) + m / (r + l)) * (1.0 + a);
      }
      double ll = sqrt(t * t + 4.0);
      crt = 2.0 / ll;
      srt = t / ll;
      clt = (crt + srt * m) / a;
      slt = (ht / ft) * srt / a;
    }
  }
  if (swp) { csl = srt; snl = crt; csr = slt; snr = clt; }
  else     { csl = clt; snl = slt; csr = crt; snr = srt; }
  double tsign = 1.0;
  if (pmax == 1) tsign = dsgn(1.0, csr) * dsgn(1.0, csl) * dsgn(1.0, f);
  if (pmax == 2) tsign = dsgn(1.0, snr) * dsgn(1.0, csl) * dsgn(1.0, g);
  if (pmax == 3) tsign = dsgn(1.0, snr) * dsgn(1.0, snl) * dsgn(1.0, h);
  ssmax = dsgn(ssmax, tsign);
  ssmin = dsgn(ssmin, tsign * dsgn(1.0, f) * dsgn(1.0, h));
}

__device__ void do_svd(const float* __restrict__ core, float* __restrict__ misc,
                       float* __restrict__ aux_out)
{
  double aux = 0.0;
  for (int hh = 0; hh < 2; hh++) {
    double a = (double)core[hh * 4 + 0];
    double b = (double)core[hh * 4 + 1];
    double c = (double)core[hh * 4 + 2];
    double d = (double)core[hh * 4 + 3];
    double tau = 0.0, v2 = 0.0, d1, e, d2;
    if (c != 0.0) {
      double nrm  = sqrt(a * a + c * c);
      double beta = (a >= 0.0) ? -nrm : nrm;
      tau = (beta - a) / beta;
      v2  = c / (a - beta);
      double wsum = b + v2 * d;
      d1 = beta;
      e  = b - tau * wsum;
      d2 = d - tau * v2 * wsum;
    } else { d1 = a; e = b; d2 = d; }
    double ssmin, ssmax, snr, csr, snl, csl;
    dlasv2_dev(d1, e, d2, ssmin, ssmax, snr, csr, snl, csl);
    double t0 = csl + v2 * snl;
    double u0 = csl - tau * t0;
    double u1 = snl - tau * v2 * t0;
    double sg = (ssmax < 0.0) ? -1.0 : 1.0;
    misc[hh * 2 + 0]     = (float)u0;
    misc[hh * 2 + 1]     = (float)u1;
    misc[4 + hh * 2 + 0] = (float)(sg * csr);
    misc[4 + hh * 2 + 1] = (float)(sg * snr);
    double s2 = fabs(ssmin);
    double rl = s2 - 0.15; if (rl < 0.0) rl = 0.0;
    aux += rl * rl;
  }
  aux_out[0] = (float)(aux * 0.1);
}

// ===== K1: fused RMS-stats + conv + gemm1, 32-row tiles. grid (64, KSPLIT). =
// Computes inv_s for its 36 rows (4 halo + 32 own) in-block with the SAME
// reduction order as the old rms_kernel (thread t owns cols 4t..4t+3,
// shfl_down 32..1, 4 wave partials) -> bitwise-identical inv_s.
__global__ __launch_bounds__(256) void convgemm1_kernel(
    const float* __restrict__ tokens, const float* __restrict__ rms_w,
    const float* __restrict__ conv_w, const float* __restrict__ conv_b,
    const float* __restrict__ wq,     const float* __restrict__ core,
    float* __restrict__ misc,         float* __restrict__ aux_out,
    float* __restrict__ qpart)
{
  __shared__ float xh[36 * 33];                    // [srow][c], stride 33
  __shared__ __align__(16) float a_lds[32 * 32];   // [k][row]
  __shared__ __align__(16) float b_lds[32 * 128];  // [k][col]
  __shared__ float inv_l[36];
  __shared__ float red[36][4];
  const int t  = threadIdx.x;
  const int rb = blockIdx.x * 32;
  const int kb = blockIdx.y * 128;
  const int n0 = rb & 1023;          // 32-aligned => whole block same batch
  const int lane = t & 63, wv = t >> 6;

  // ---- in-block RMS stats for rows rb-4 .. rb+31 (36 rows) ----
  {
    const int c0 = t * 4;
    for (int s = 0; s < 36; s++) {
      float sq = 0.0f;
      if (n0 - 4 + s >= 0) {
        float4 v = *(const float4*)(tokens + (size_t)(rb - 4 + s) * 1024 + c0);
        sq = v.x * v.x + v.y * v.y + v.z * v.z + v.w * v.w;
      }
      #pragma unroll
      for (int off = 32; off; off >>= 1) sq += __shfl_down(sq, off, 64);
      if (lane == 0) red[s][wv] = sq;
    }
    if (blockIdx.x == 0 && blockIdx.y == 0 && t == 0) do_svd(core, misc, aux_out);
    __syncthreads();
    if (t < 36)
      inv_l[t] = (n0 - 4 + t >= 0)
        ? rsqrtf((red[t][0] + red[t][1] + red[t][2] + red[t][3]) * (1.0f / 1024.0f)
                 + 1.1920929e-07f)
        : 0.0f;
    // barrier before first xh staging happens inside the kt loop below
  }

  const int tx = t & 31, ty = t >> 5;
  const int c0g = tx * 4, r0 = ty * 4;
  float acc[4][4];
  #pragma unroll
  for (int i = 0; i < 4; i++)
    #pragma unroll
    for (int j = 0; j < 4; j++) acc[i][j] = 0.0f;

  const int ob = t >> 1, kqb = (t & 1) * 16;   // wq staging map
  const int cr = t & 31;                       // conv: row
  const int ch = (t >> 5) * 4;                 // conv: col base (4 cols/thread)

  for (int kt = 0; kt < 4; kt++) {
    const int k0 = kb + kt * 32;
    __syncthreads();                 // inv_l ready (kt=0) / prev GEMM done
    #pragma unroll
    for (int it = 0; it < 2; it++) {
      int idx  = it * 256 + t;
      int srow = idx >> 3, f4 = (idx & 7) * 4;
      if (srow < 36) {
        float4 v = make_float4(0.f, 0.f, 0.f, 0.f);
        if (n0 - 4 + srow >= 0)
          v = *(const float4*)(tokens + (size_t)(rb - 4 + srow) * 1024 + k0 + f4);
        float iv = inv_l[srow];
        xh[srow * 33 + f4 + 0] = v.x * iv;
        xh[srow * 33 + f4 + 1] = v.y * iv;
        xh[srow * 33 + f4 + 2] = v.z * iv;
        xh[srow * 33 + f4 + 3] = v.w * iv;
      }
    }
    {
      const float* bp = wq + (size_t)ob * 1024 + k0 + kqb;
      float4 b0 = *(const float4*)(bp);
      float4 b1 = *(const float4*)(bp + 4);
      float4 b2 = *(const float4*)(bp + 8);
      float4 b3 = *(const float4*)(bp + 12);
      b_lds[(kqb +  0) * 128 + ob] = b0.x;  b_lds[(kqb +  1) * 128 + ob] = b0.y;
      b_lds[(kqb +  2) * 128 + ob] = b0.z;  b_lds[(kqb +  3) * 128 + ob] = b0.w;
      b_lds[(kqb +  4) * 128 + ob] = b1.x;  b_lds[(kqb +  5) * 128 + ob] = b1.y;
      b_lds[(kqb +  6) * 128 + ob] = b1.z;  b_lds[(kqb +  7) * 128 + ob] = b1.w;
      b_lds[(kqb +  8) * 128 + ob] = b2.x;  b_lds[(kqb +  9) * 128 + ob] = b2.y;
      b_lds[(kqb + 10) * 128 + ob] = b2.z;  b_lds[(kqb + 11) * 128 + ob] = b2.w;
      b_lds[(kqb + 12) * 128 + ob] = b3.x;  b_lds[(kqb + 13) * 128 + ob] = b3.y;
      b_lds[(kqb + 14) * 128 + ob] = b3.z;  b_lds[(kqb + 15) * 128 + ob] = b3.w;
    }
    __syncthreads();
    #pragma unroll
    for (int i = 0; i < 4; i++) {
      const int c = ch + i;
      const float* cw = conv_w + (size_t)(k0 + c) * 5;
      float a = xh[(cr + 0) * 33 + c] * cw[0]
              + xh[(cr + 1) * 33 + c] * cw[1]
              + xh[(cr + 2) * 33 + c] * cw[2]
              + xh[(cr + 3) * 33 + c] * cw[3]
              + xh[(cr + 4) * 33 + c] * cw[4];
      a_lds[c * 32 + cr] = a * rms_w[k0 + c] + conv_b[k0 + c];
    }
    __syncthreads();
    #pragma unroll
    for (int k = 0; k < 32; k++) {
      float4 av = *(const float4*)(a_lds + k * 32 + r0);
      float4 bv = *(const float4*)(b_lds + k * 128 + c0g);
      float ar[4] = {av.x, av.y, av.z, av.w};
      float br[4] = {bv.x, bv.y, bv.z, bv.w};
      #pragma unroll
      for (int i = 0; i < 4; i++)
        #pragma unroll
        for (int j = 0; j < 4; j++)
          acc[i][j] = fmaf(ar[i], br[j], acc[i][j]);
    }
  }
  float* C = qpart + (size_t)blockIdx.y * (ROWS * 128);
  #pragma unroll
  for (int i = 0; i < 4; i++) {
    float4 o4; o4.x = acc[i][0]; o4.y = acc[i][1]; o4.z = acc[i][2]; o4.w = acc[i][3];
    *(float4*)(C + (size_t)(rb + r0 + i) * 128 + c0g) = o4;
  }
}

// ========== K2: gemm2 with fused plane-reduce + LayerNorm (A side) =========
__global__ __launch_bounds__(256) void gemm2ln_kernel(const float* __restrict__ qpart,
                                                      const float* __restrict__ qln_w,
                                                      const float* __restrict__ keys,
                                                      float* __restrict__ C)
{
  __shared__ __align__(16) float a_l[128 * 32];     // [k][row], normalized
  __shared__ __align__(16) float b_lds[32 * 128];   // [k][col]
  const int t  = threadIdx.x;
  const int rb = blockIdx.x * 32;
  const int cb = blockIdx.y * 128;

  const int l32 = t & 31;          // k cols l32*4 .. +3
  const int g32 = t >> 5;          // rows g32 + 8*j
  float vs[4][4];
  #pragma unroll
  for (int j = 0; j < 4; j++) { vs[j][0]=0.f; vs[j][1]=0.f; vs[j][2]=0.f; vs[j][3]=0.f; }
  #pragma unroll
  for (int g = 0; g < KSPLIT; g++) {
    const float* pg = qpart + (size_t)g * (ROWS * 128) + (size_t)rb * 128 + l32 * 4;
    #pragma unroll
    for (int j = 0; j < 4; j++) {
      float4 v = *(const float4*)(pg + (g32 + 8 * j) * 128);
      vs[j][0] += v.x; vs[j][1] += v.y; vs[j][2] += v.z; vs[j][3] += v.w;
    }
  }
  float4 qw = *(const float4*)(qln_w + l32 * 4);
  #pragma unroll
  for (int j = 0; j < 4; j++) {
    float s1 = vs[j][0] + vs[j][1] + vs[j][2] + vs[j][3];
    #pragma unroll
    for (int off = 16; off; off >>= 1) s1 += __shfl_xor(s1, off, 32);
    float mu = s1 * (1.0f / 128.0f);
    float d0 = vs[j][0] - mu, d1 = vs[j][1] - mu, d2 = vs[j][2] - mu, d3 = vs[j][3] - mu;
    float s2 = d0 * d0 + d1 * d1 + d2 * d2 + d3 * d3;
    #pragma unroll
    for (int off = 16; off; off >>= 1) s2 += __shfl_xor(s2, off, 32);
    float rstd = rsqrtf(s2 * (1.0f / 128.0f) + 1e-5f);
    const int row = g32 + 8 * j;
    a_l[(l32 * 4 + 0) * 32 + row] = d0 * rstd * qw.x;
    a_l[(l32 * 4 + 1) * 32 + row] = d1 * rstd * qw.y;
    a_l[(l32 * 4 + 2) * 32 + row] = d2 * rstd * qw.z;
    a_l[(l32 * 4 + 3) * 32 + row] = d3 * rstd * qw.w;
  }
  __syncthreads();

  const int tx = t & 31, ty = t >> 5;
  const int c0 = tx * 4, r0 = ty * 4;
  float acc[4][4];
  #pragma unroll
  for (int i = 0; i < 4; i++)
    #pragma unroll
    for (int j = 0; j < 4; j++) acc[i][j] = 0.0f;

  const int ob = t >> 1, kqb = (t & 1) * 16;
  for (int kt = 0; kt < 4; kt++) {
    const int k0 = kt * 32;
    {
      const float* bp = keys + (size_t)(cb + ob) * 128 + k0 + kqb;
      float4 b0 = *(const float4*)(bp);
      float4 b1 = *(const float4*)(bp + 4);
      float4 b2 = *(const float4*)(bp + 8);
      float4 b3 = *(const float4*)(bp + 12);
      b_lds[(kqb +  0) * 128 + ob] = b0.x;  b_lds[(kqb +  1) * 128 + ob] = b0.y;
      b_lds[(kqb +  2) * 128 + ob] = b0.z;  b_lds[(kqb +  3) * 128 + ob] = b0.w;
      b_lds[(kqb +  4) * 128 + ob] = b1.x;  b_lds[(kqb +  5) * 128 + ob] = b1.y;
      b_lds[(kqb +  6) * 128 + ob] = b1.z;  b_lds[(kqb +  7) * 128 + ob] = b1.w;
      b_lds[(kqb +  8) * 128 + ob] = b2.x;  b_lds[(kqb +  9) * 128 + ob] = b2.y;
      b_lds[(kqb + 10) * 128 + ob] = b2.z;  b_lds[(kqb + 11) * 128 + ob] = b2.w;
      b_lds[(kqb + 12) * 128 + ob] = b3.x;  b_lds[(kqb + 13) * 128 + ob] = b3.y;
      b_lds[(kqb + 14) * 128 + ob] = b3.z;  b_lds[(kqb + 15) * 128 + ob] = b3.w;
    }
    __syncthreads();
    #pragma unroll
    for (int k = 0; k < 32; k++) {
      float4 av = *(const float4*)(a_l + (k0 + k) * 32 + r0);
      float4 bv = *(const float4*)(b_lds + k * 128 + c0);
      float ar[4] = {av.x, av.y, av.z, av.w};
      float br[4] = {bv.x, bv.y, bv.z, bv.w};
      #pragma unroll
      for (int i = 0; i < 4; i++)
        #pragma unroll
        for (int j = 0; j < 4; j++)
          acc[i][j] = fmaf(ar[i], br[j], acc[i][j]);
    }
    __syncthreads();
  }
  #pragma unroll
  for (int i = 0; i < 4; i++) {
    float4 o4; o4.x = acc[i][0]; o4.y = acc[i][1]; o4.z = acc[i][2]; o4.w = acc[i][3];
    *(float4*)(C + (size_t)(rb + r0 + i) * 1024 + cb + c0) = o4;
  }
}

// ======================== ballot radix-select helpers =======================
__device__ inline unsigned f2ord(float f) {
  unsigned u = __float_as_uint(f);
  return (u & 0x80000000u) ? ~u : (u | 0x80000000u);
}
__device__ inline int lpc(unsigned long long m) {
  return __builtin_amdgcn_mbcnt_hi((unsigned)(m >> 32),
         __builtin_amdgcn_mbcnt_lo((unsigned)m, 0));
}

// ======= K3: fused tail (R7 form): select w/ early-exit, then gather ========
__global__ __launch_bounds__(256) void tail_kernel(const float* __restrict__ sc,
                                                   const float* __restrict__ misc,
                                                   const float* __restrict__ core,
                                                   const float* __restrict__ memories,
                                                   float* __restrict__ out)
{
  __shared__ __align__(16) float s_pl[1024];
  __shared__ int   tkbuf[4][32];
  __shared__ float mvals[4][32];
  __shared__ int   mcand[4][32];
  __shared__ int   s_idx[64];
  __shared__ float s_w[64];

  const int row = blockIdx.x;
  const int tid = threadIdx.x;
  ((float4*)s_pl)[tid] = ((const float4*)(sc + (size_t)row * 1024))[tid];
  __syncthreads();

  const int w = tid >> 6, lane = tid & 63;

  // ---- phase 1: wave w -> (head = w>>1, side = w&1), top-32 of 256 ----
  {
    const int h = w >> 1, side = w & 1;
    const float v0 = misc[side * 4 + h * 2 + 0];
    const float v1 = misc[side * 4 + h * 2 + 1];
    const float* p0 = s_pl + side * 512;
    const float* p1 = p0 + 256;
    const int mb = lane * 4;
    float4 a4 = *(const float4*)(p0 + mb);
    float4 b4 = *(const float4*)(p1 + mb);
    unsigned kk[4];
    kk[0] = f2ord(a4.x * v0 + b4.x * v1);
    kk[1] = f2ord(a4.y * v0 + b4.y * v1);
    kk[2] = f2ord(a4.z * v0 + b4.z * v1);
    kk[3] = f2ord(a4.w * v0 + b4.w * v1);
    unsigned tau = 0u;
    for (int b = 31; b >= 0; --b) {
      unsigned cand = tau | (1u << b);
      int cnt = 0;
      #pragma unroll
      for (int i = 0; i < 4; i++) cnt += __popcll(__ballot(kk[i] >= cand));
      if (cnt >= 32) {
        tau = cand;
        if (cnt == 32) break;   // exact top-32 set determined
      }
    }
    unsigned long long bG[4], bE[4];
    int cntG = 0, sbG = 0, sbE = 0;
    #pragma unroll
    for (int i = 0; i < 4; i++) {
      bG[i] = __ballot(kk[i] > tau);
      bE[i] = __ballot(kk[i] == tau);
      cntG += __popcll(bG[i]);
      sbG  += lpc(bG[i]);
      sbE  += lpc(bE[i]);
    }
    const int need = 32 - cntG;
    int runG = 0, runE = 0;
    #pragma unroll
    for (int i = 0; i < 4; i++) {
      if (kk[i] > tau)       { tkbuf[w][sbG + runG] = mb + i; runG++; }
      else if (kk[i] == tau) {
        int r = sbE + runE;
        if (r < need) tkbuf[w][cntG + r] = mb + i;
        runE++;
      }
    }
  }
  __syncthreads();

  // ---- phase 2: wave w -> (head = w>>1, half = w&1), top-32 of 512 ----
  {
    const int h = w >> 1, half = w & 1;
    const float c00 = core[h * 4 + 0], c01 = core[h * 4 + 1];
    const float c10 = core[h * 4 + 2], c11 = core[h * 4 + 3];
    const int i_glob = half * 16 + (lane >> 2);
    const int ri = tkbuf[h * 2 + 0][i_glob];
    const float fr0 = s_pl[ri], fr1 = s_pl[256 + ri];
    const float a0 = fr0 * c00 + fr1 * c10;
    const float a1 = fr0 * c01 + fr1 * c11;
    const int j0 = (lane & 3) * 8;
    float sv[8];
    unsigned kk[8];
    #pragma unroll
    for (int t2 = 0; t2 < 8; t2++) {
      int cj = tkbuf[h * 2 + 1][j0 + t2];
      sv[t2] = a0 * s_pl[512 + cj] + a1 * s_pl[768 + cj];
      kk[t2] = f2ord(sv[t2]);
    }
    unsigned tau = 0u;
    for (int b = 31; b >= 0; --b) {
      unsigned cand = tau | (1u << b);
      int cnt = 0;
      #pragma unroll
      for (int i = 0; i < 8; i++) cnt += __popcll(__ballot(kk[i] >= cand));
      if (cnt >= 32) {
        tau = cand;
        if (cnt == 32) break;   // exact top-32 set determined
      }
    }
    unsigned long long bG[8], bE[8];
    int cntG = 0, sbG = 0, sbE = 0;
    #pragma unroll
    for (int i = 0; i < 8; i++) {
      bG[i] = __ballot(kk[i] > tau);
      bE[i] = __ballot(kk[i] == tau);
      cntG += __popcll(bG[i]);
      sbG  += lpc(bG[i]);
      sbE  += lpc(bE[i]);
    }
    const int need = 32 - cntG;
    int runG = 0, runE = 0;
    #pragma unroll
    for (int i = 0; i < 8; i++) {
      int c = i_glob * 32 + j0 + i;
      if (kk[i] > tau) {
        mvals[w][sbG + runG] = sv[i]; mcand[w][sbG + runG] = c; runG++;
      } else if (kk[i] == tau) {
        int r = sbE + runE;
        if (r < need) { mvals[w][cntG + r] = sv[i]; mcand[w][cntG + r] = c; }
        runE++;
      }
    }
  }
  __syncthreads();

  // ---- merge two half-lists per head by rank-count ----
  if (w < 2) {
    const int h = w;
    const int half2 = lane >> 5, k = lane & 31;
    const float v = mvals[h * 2 + half2][k];
    const int   c = mcand[h * 2 + half2][k];
    int cnt = 0;
    #pragma unroll 8
    for (int j = 0; j < 64; j++) {
      float u = mvals[h * 2 + (j >> 5)][j & 31];
      int  uc = mcand[h * 2 + (j >> 5)][j & 31];
      cnt += (u > v || (u == v && uc < c)) ? 1 : 0;
    }
    if (cnt < 32) {
      int ii = c >> 5, jj = c & 31;
      s_idx[h * 32 + cnt] = tkbuf[h * 2][ii] * 256 + tkbuf[h * 2 + 1][jj];
      s_w[h * 32 + cnt]   = 1.0f / (1.0f + expf(-v));
    }
  }
  __syncthreads();

  // ---- weighted gather-sum: double-buffered batches of 8 loads ----
  const int h2 = tid >> 7;
  const int d4 = tid & 127;
  const int base = h2 * 32;
  const float* mb = memories + d4 * 4;
  float ax = 0.f, ay = 0.f, az = 0.f, aw = 0.f;
  float4 va[8], vb[8];
  float  wa[8], wb[8];
  #pragma unroll
  for (int i = 0; i < 8; i++) {
    int mi = s_idx[base + i]; wa[i] = s_w[base + i];
    va[i] = *(const float4*)(mb + (size_t)mi * 512);
  }
  #pragma unroll
  for (int i = 0; i < 8; i++) {
    int mi = s_idx[base + 8 + i]; wb[i] = s_w[base + 8 + i];
    vb[i] = *(const float4*)(mb + (size_t)mi * 512);
  }
  #pragma unroll
  for (int i = 0; i < 8; i++) {
    ax = fmaf(wa[i], va[i].x, ax); ay = fmaf(wa[i], va[i].y, ay);
    az = fmaf(wa[i], va[i].z, az); aw = fmaf(wa[i], va[i].w, aw);
  }
  #pragma unroll
  for (int i = 0; i < 8; i++) {
    int mi = s_idx[base + 16 + i]; wa[i] = s_w[base + 16 + i];
    va[i] = *(const float4*)(mb + (size_t)mi * 512);
  }
  #pragma unroll
  for (int i = 0; i < 8; i++) {
    ax = fmaf(wb[i], vb[i].x, ax); ay = fmaf(wb[i], vb[i].y, ay);
    az = fmaf(wb[i], vb[i].z, az); aw = fmaf(wb[i], vb[i].w, aw);
  }
  #pragma unroll
  for (int i = 0; i < 8; i++) {
    int mi = s_idx[base + 24 + i]; wb[i] = s_w[base + 24 + i];
    vb[i] = *(const float4*)(mb + (size_t)mi * 512);
  }
  #pragma unroll
  for (int i = 0; i < 8; i++) {
    ax = fmaf(wa[i], va[i].x, ax); ay = fmaf(wa[i], va[i].y, ay);
    az = fmaf(wa[i], va[i].z, az); aw = fmaf(wa[i], va[i].w, aw);
  }
  #pragma unroll
  for (int i = 0; i < 8; i++) {
    ax = fmaf(wb[i], vb[i].x, ax); ay = fmaf(wb[i], vb[i].y, ay);
    az = fmaf(wb[i], vb[i].z, az); aw = fmaf(wb[i], vb[i].w, aw);
  }
  float4 o4; o4.x = ax; o4.y = ay; o4.z = az; o4.w = aw;
  ((float4*)out)[(size_t)row * 256 + tid] = o4;
}

// ============================== launcher ====================================
extern "C" void kernel_launch(void* const* d_in, const int* in_sizes, int n_in,
                              void* d_out, int out_size, void* d_ws, size_t ws_size,
                              hipStream_t stream) {
  const float* tokens = (const float*)d_in[0];
  const float* rms_w  = (const float*)d_in[1];
  const float* conv_w = (const float*)d_in[2];
  const float* conv_b = (const float*)d_in[3];
  const float* wq     = (const float*)d_in[4];
  const float* qln_w  = (const float*)d_in[5];
  const float* keys   = (const float*)d_in[6];
  const float* core   = (const float*)d_in[7];
  const float* mems   = (const float*)d_in[8];
  float* out = (float*)d_out;
  float* ws  = (float*)d_ws;

  // workspace layout (floats)
  float* misc  = ws;                       // 8
  float* qpart = ws + 4096;                // KSPLIT * 2048*128 = 2,097,152
  float* sc    = qpart + 2097152;          // 2048*1024

  convgemm1_kernel<<<dim3(64, KSPLIT), 256, 0, stream>>>(tokens, rms_w, conv_w,
                                                         conv_b, wq, core, misc,
                                                         out + 2097152, qpart);
  gemm2ln_kernel <<<dim3(64, 8), 256, 0, stream>>>(qpart, qln_w, keys, sc);
  tail_kernel    <<<ROWS, 256, 0, stream>>>(sc, misc, core, mems, out);
}

// Round 12
// 272.206 us; speedup vs baseline: 1.2221x; 1.0551x over previous
//
#include <hip/hip_runtime.h>
#include <math.h>

// ---------------------------------------------------------------------------
// UltraMem forward, MI355X. B=2 N=1024 DIM=1024 DQK=128 NUM_KEYS=256 TOPK=32
// RANK=2 HEADS=2 DV=512 KCONV=5.
// R12: pure revert to R7 (best verified 273.7us). R8/R10/R11 all regressed:
//   - tail: 2048-block float4-gather + early-exit select = local optimum
//     (random-2KB-gather HBM efficiency limit; TLP restructures lost more)
//   - front: rms/convgemm1/gemm2ln = 29.5us incl gaps (R9-measured), shape-
//     insensitive; rms-fold into convgemm1 regressed (R11)
//   - fills ~153us of dur are harness re-poison, at 85% HBM peak (R3 equation)
// ---------------------------------------------------------------------------

#define ROWS 2048            // B*N
#define KSPLIT 8             // gemm1 K partitions

// ======================= 2x2 SVD (LAPACK dgesdd replica) ====================
__device__ inline double dsgn(double x, double y) { return (y >= 0.0) ? fabs(x) : -fabs(x); }

__device__ void dlasv2_dev(double f, double g, double h,
                           double& ssmin, double& ssmax,
                           double& snr, double& csr, double& snl, double& csl)
{
  const double EPSD = 2.2204460492503131e-16;
  double ft = f, fa = fabs(f), ht = h, ha = fabs(h);
  int pmax = 1;
  bool swp = (ha > fa);
  if (swp) { pmax = 3; double tp = ft; ft = ht; ht = tp; tp = fa; fa = ha; ha = tp; }
  double gt = g, ga = fabs(gt);
  double clt = 0.0, crt = 0.0, slt = 0.0, srt = 0.0;
  if (ga == 0.0) {
    ssmin = ha; ssmax = fa; clt = 1.0; crt = 1.0; slt = 0.0; srt = 0.0;
  } else {
    bool gasmal = true;
    if (ga > fa) {
      pmax = 2;
      if ((fa / ga) < EPSD) {
        gasmal = false;
        ssmax = ga;
        if (ha > 1.0) ssmin = fa / (ga / ha); else ssmin = (fa / ga) * ha;
        clt = 1.0; slt = ht / gt; srt = 1.0; crt = ft / gt;
      }
    }
    if (gasmal) {
      double dd = fa - ha, l;
      if (dd == fa) l = 1.0; else l = dd / fa;
      double m  = gt / ft;
      double t  = 2.0 - l;
      double mm = m * m, tt = t * t;
      double s  = sqrt(tt + mm);
      double r  = (l == 0.0) ? fabs(m) : sqrt(l * l + mm);
      double a  = 0.5 * (s + r);
      ssmin = ha / a;
      ssmax = fa * a;
      if (mm == 0.0) {
        if (l == 0.0) t = dsgn(2.0, ft) * dsgn(1.0, gt);
        else          t = gt / dsgn(dd, ft) + m / t;
      } else {
        t = (m / (s + t) + m / (r + l)) * (1.0 + a);
      }
      double ll = sqrt(t * t + 4.0);
      crt = 2.0 / ll;
      srt = t / ll;
      clt = (crt + srt * m) / a;
      slt = (ht / ft) * srt / a;
    }
  }
  if (swp) { csl = srt; snl = crt; csr = slt; snr = clt; }
  else     { csl = clt; snl = slt; csr = crt; snr = srt; }
  double tsign = 1.0;
  if (pmax == 1) tsign = dsgn(1.0, csr) * dsgn(1.0, csl) * dsgn(1.0, f);
  if (pmax == 2) tsign = dsgn(1.0, snr) * dsgn(1.0, csl) * dsgn(1.0, g);
  if (pmax == 3) tsign = dsgn(1.0, snr) * dsgn(1.0, snl) * dsgn(1.0, h);
  ssmax = dsgn(ssmax, tsign);
  ssmin = dsgn(ssmin, tsign * dsgn(1.0, f) * dsgn(1.0, h));
}

__device__ void do_svd(const float* __restrict__ core, float* __restrict__ misc,
                       float* __restrict__ aux_out)
{
  double aux = 0.0;
  for (int hh = 0; hh < 2; hh++) {
    double a = (double)core[hh * 4 + 0];
    double b = (double)core[hh * 4 + 1];
    double c = (double)core[hh * 4 + 2];
    double d = (double)core[hh * 4 + 3];
    double tau = 0.0, v2 = 0.0, d1, e, d2;
    if (c != 0.0) {
      double nrm  = sqrt(a * a + c * c);
      double beta = (a >= 0.0) ? -nrm : nrm;
      tau = (beta - a) / beta;
      v2  = c / (a - beta);
      double wsum = b + v2 * d;
      d1 = beta;
      e  = b - tau * wsum;
      d2 = d - tau * v2 * wsum;
    } else { d1 = a; e = b; d2 = d; }
    double ssmin, ssmax, snr, csr, snl, csl;
    dlasv2_dev(d1, e, d2, ssmin, ssmax, snr, csr, snl, csl);
    double t0 = csl + v2 * snl;
    double u0 = csl - tau * t0;
    double u1 = snl - tau * v2 * t0;
    double sg = (ssmax < 0.0) ? -1.0 : 1.0;
    misc[hh * 2 + 0]     = (float)u0;
    misc[hh * 2 + 1]     = (float)u1;
    misc[4 + hh * 2 + 0] = (float)(sg * csr);
    misc[4 + hh * 2 + 1] = (float)(sg * snr);
    double s2 = fabs(ssmin);
    double rl = s2 - 0.15; if (rl < 0.0) rl = 0.0;
    aux += rl * rl;
  }
  aux_out[0] = (float)(aux * 0.1);
}

// ================== K0: per-row RMS inv_s (8 rows/block) + SVD ==============
__global__ __launch_bounds__(256) void rms_kernel(const float* __restrict__ tokens,
                                                  const float* __restrict__ core,
                                                  float* __restrict__ inv_sg,
                                                  float* __restrict__ misc,
                                                  float* __restrict__ aux_out)
{
  __shared__ float red[8][4];
  const int t    = threadIdx.x;
  const int row0 = blockIdx.x * 8;
  const int c0   = t * 4;
  float sq[8];
  #pragma unroll
  for (int s = 0; s < 8; s++) {
    float4 v = *(const float4*)(tokens + (size_t)(row0 + s) * 1024 + c0);
    sq[s] = v.x * v.x + v.y * v.y + v.z * v.z + v.w * v.w;
  }
  #pragma unroll
  for (int off = 32; off; off >>= 1) {
    #pragma unroll
    for (int s = 0; s < 8; s++) sq[s] += __shfl_down(sq[s], off, 64);
  }
  const int lane = t & 63, w = t >> 6;
  if (lane == 0) {
    #pragma unroll
    for (int s = 0; s < 8; s++) red[s][w] = sq[s];
  }
  __syncthreads();
  if (t < 8)
    inv_sg[row0 + t] = rsqrtf((red[t][0] + red[t][1] + red[t][2] + red[t][3])
                              * (1.0f / 1024.0f) + 1.1920929e-07f);
  if (blockIdx.x == 0 && t == 0) do_svd(core, misc, aux_out);
}

// ===== K1: fused conv + gemm1, 32-row tiles. grid (64, KSPLIT). =============
__global__ __launch_bounds__(256) void convgemm1_kernel(
    const float* __restrict__ tokens, const float* __restrict__ inv_sg,
    const float* __restrict__ rms_w,  const float* __restrict__ conv_w,
    const float* __restrict__ conv_b, const float* __restrict__ wq,
    float* __restrict__ qpart)
{
  __shared__ float xh[36 * 33];                    // [srow][c], stride 33
  __shared__ __align__(16) float a_lds[32 * 32];   // [k][row]
  __shared__ __align__(16) float b_lds[32 * 128];  // [k][col]
  __shared__ float inv_l[36];
  const int t  = threadIdx.x;
  const int rb = blockIdx.x * 32;
  const int kb = blockIdx.y * 128;
  const int n0 = rb & 1023;          // 32-aligned => whole block same batch

  if (t < 36) inv_l[t] = (n0 - 4 + t >= 0) ? inv_sg[rb - 4 + t] : 0.0f;

  const int tx = t & 31, ty = t >> 5;
  const int c0g = tx * 4, r0 = ty * 4;
  float acc[4][4];
  #pragma unroll
  for (int i = 0; i < 4; i++)
    #pragma unroll
    for (int j = 0; j < 4; j++) acc[i][j] = 0.0f;

  const int ob = t >> 1, kqb = (t & 1) * 16;   // wq staging map
  const int cr = t & 31;                       // conv: row
  const int ch = (t >> 5) * 4;                 // conv: col base (4 cols/thread)

  for (int kt = 0; kt < 4; kt++) {
    const int k0 = kb + kt * 32;
    __syncthreads();                 // prev GEMM done before overwriting LDS
    #pragma unroll
    for (int it = 0; it < 2; it++) {
      int idx  = it * 256 + t;
      int srow = idx >> 3, f4 = (idx & 7) * 4;
      if (srow < 36) {
        float4 v = make_float4(0.f, 0.f, 0.f, 0.f);
        if (n0 - 4 + srow >= 0)
          v = *(const float4*)(tokens + (size_t)(rb - 4 + srow) * 1024 + k0 + f4);
        float iv = inv_l[srow];
        xh[srow * 33 + f4 + 0] = v.x * iv;
        xh[srow * 33 + f4 + 1] = v.y * iv;
        xh[srow * 33 + f4 + 2] = v.z * iv;
        xh[srow * 33 + f4 + 3] = v.w * iv;
      }
    }
    {
      const float* bp = wq + (size_t)ob * 1024 + k0 + kqb;
      float4 b0 = *(const float4*)(bp);
      float4 b1 = *(const float4*)(bp + 4);
      float4 b2 = *(const float4*)(bp + 8);
      float4 b3 = *(const float4*)(bp + 12);
      b_lds[(kqb +  0) * 128 + ob] = b0.x;  b_lds[(kqb +  1) * 128 + ob] = b0.y;
      b_lds[(kqb +  2) * 128 + ob] = b0.z;  b_lds[(kqb +  3) * 128 + ob] = b0.w;
      b_lds[(kqb +  4) * 128 + ob] = b1.x;  b_lds[(kqb +  5) * 128 + ob] = b1.y;
      b_lds[(kqb +  6) * 128 + ob] = b1.z;  b_lds[(kqb +  7) * 128 + ob] = b1.w;
      b_lds[(kqb +  8) * 128 + ob] = b2.x;  b_lds[(kqb +  9) * 128 + ob] = b2.y;
      b_lds[(kqb + 10) * 128 + ob] = b2.z;  b_lds[(kqb + 11) * 128 + ob] = b2.w;
      b_lds[(kqb + 12) * 128 + ob] = b3.x;  b_lds[(kqb + 13) * 128 + ob] = b3.y;
      b_lds[(kqb + 14) * 128 + ob] = b3.z;  b_lds[(kqb + 15) * 128 + ob] = b3.w;
    }
    __syncthreads();
    #pragma unroll
    for (int i = 0; i < 4; i++) {
      const int c = ch + i;
      const float* cw = conv_w + (size_t)(k0 + c) * 5;
      float a = xh[(cr + 0) * 33 + c] * cw[0]
              + xh[(cr + 1) * 33 + c] * cw[1]
              + xh[(cr + 2) * 33 + c] * cw[2]
              + xh[(cr + 3) * 33 + c] * cw[3]
              + xh[(cr + 4) * 33 + c] * cw[4];
      a_lds[c * 32 + cr] = a * rms_w[k0 + c] + conv_b[k0 + c];
    }
    __syncthreads();
    #pragma unroll
    for (int k = 0; k < 32; k++) {
      float4 av = *(const float4*)(a_lds + k * 32 + r0);
      float4 bv = *(const float4*)(b_lds + k * 128 + c0g);
      float ar[4] = {av.x, av.y, av.z, av.w};
      float br[4] = {bv.x, bv.y, bv.z, bv.w};
      #pragma unroll
      for (int i = 0; i < 4; i++)
        #pragma unroll
        for (int j = 0; j < 4; j++)
          acc[i][j] = fmaf(ar[i], br[j], acc[i][j]);
    }
  }
  float* C = qpart + (size_t)blockIdx.y * (ROWS * 128);
  #pragma unroll
  for (int i = 0; i < 4; i++) {
    float4 o4; o4.x = acc[i][0]; o4.y = acc[i][1]; o4.z = acc[i][2]; o4.w = acc[i][3];
    *(float4*)(C + (size_t)(rb + r0 + i) * 128 + c0g) = o4;
  }
}

// ========== K2: gemm2 with fused plane-reduce + LayerNorm (A side) =========
__global__ __launch_bounds__(256) void gemm2ln_kernel(const float* __restrict__ qpart,
                                                      const float* __restrict__ qln_w,
                                                      const float* __restrict__ keys,
                                                      float* __restrict__ C)
{
  __shared__ __align__(16) float a_l[128 * 32];     // [k][row], normalized
  __shared__ __align__(16) float b_lds[32 * 128];   // [k][col]
  const int t  = threadIdx.x;
  const int rb = blockIdx.x * 32;
  const int cb = blockIdx.y * 128;

  const int l32 = t & 31;          // k cols l32*4 .. +3
  const int g32 = t >> 5;          // rows g32 + 8*j
  float vs[4][4];
  #pragma unroll
  for (int j = 0; j < 4; j++) { vs[j][0]=0.f; vs[j][1]=0.f; vs[j][2]=0.f; vs[j][3]=0.f; }
  #pragma unroll
  for (int g = 0; g < KSPLIT; g++) {
    const float* pg = qpart + (size_t)g * (ROWS * 128) + (size_t)rb * 128 + l32 * 4;
    #pragma unroll
    for (int j = 0; j < 4; j++) {
      float4 v = *(const float4*)(pg + (g32 + 8 * j) * 128);
      vs[j][0] += v.x; vs[j][1] += v.y; vs[j][2] += v.z; vs[j][3] += v.w;
    }
  }
  float4 qw = *(const float4*)(qln_w + l32 * 4);
  #pragma unroll
  for (int j = 0; j < 4; j++) {
    float s1 = vs[j][0] + vs[j][1] + vs[j][2] + vs[j][3];
    #pragma unroll
    for (int off = 16; off; off >>= 1) s1 += __shfl_xor(s1, off, 32);
    float mu = s1 * (1.0f / 128.0f);
    float d0 = vs[j][0] - mu, d1 = vs[j][1] - mu, d2 = vs[j][2] - mu, d3 = vs[j][3] - mu;
    float s2 = d0 * d0 + d1 * d1 + d2 * d2 + d3 * d3;
    #pragma unroll
    for (int off = 16; off; off >>= 1) s2 += __shfl_xor(s2, off, 32);
    float rstd = rsqrtf(s2 * (1.0f / 128.0f) + 1e-5f);
    const int row = g32 + 8 * j;
    a_l[(l32 * 4 + 0) * 32 + row] = d0 * rstd * qw.x;
    a_l[(l32 * 4 + 1) * 32 + row] = d1 * rstd * qw.y;
    a_l[(l32 * 4 + 2) * 32 + row] = d2 * rstd * qw.z;
    a_l[(l32 * 4 + 3) * 32 + row] = d3 * rstd * qw.w;
  }
  __syncthreads();

  const int tx = t & 31, ty = t >> 5;
  const int c0 = tx * 4, r0 = ty * 4;
  float acc[4][4];
  #pragma unroll
  for (int i = 0; i < 4; i++)
    #pragma unroll
    for (int j = 0; j < 4; j++) acc[i][j] = 0.0f;

  const int ob = t >> 1, kqb = (t & 1) * 16;
  for (int kt = 0; kt < 4; kt++) {
    const int k0 = kt * 32;
    {
      const float* bp = keys + (size_t)(cb + ob) * 128 + k0 + kqb;
      float4 b0 = *(const float4*)(bp);
      float4 b1 = *(const float4*)(bp + 4);
      float4 b2 = *(const float4*)(bp + 8);
      float4 b3 = *(const float4*)(bp + 12);
      b_lds[(kqb +  0) * 128 + ob] = b0.x;  b_lds[(kqb +  1) * 128 + ob] = b0.y;
      b_lds[(kqb +  2) * 128 + ob] = b0.z;  b_lds[(kqb +  3) * 128 + ob] = b0.w;
      b_lds[(kqb +  4) * 128 + ob] = b1.x;  b_lds[(kqb +  5) * 128 + ob] = b1.y;
      b_lds[(kqb +  6) * 128 + ob] = b1.z;  b_lds[(kqb +  7) * 128 + ob] = b1.w;
      b_lds[(kqb +  8) * 128 + ob] = b2.x;  b_lds[(kqb +  9) * 128 + ob] = b2.y;
      b_lds[(kqb + 10) * 128 + ob] = b2.z;  b_lds[(kqb + 11) * 128 + ob] = b2.w;
      b_lds[(kqb + 12) * 128 + ob] = b3.x;  b_lds[(kqb + 13) * 128 + ob] = b3.y;
      b_lds[(kqb + 14) * 128 + ob] = b3.z;  b_lds[(kqb + 15) * 128 + ob] = b3.w;
    }
    __syncthreads();
    #pragma unroll
    for (int k = 0; k < 32; k++) {
      float4 av = *(const float4*)(a_l + (k0 + k) * 32 + r0);
      float4 bv = *(const float4*)(b_lds + k * 128 + c0);
      float ar[4] = {av.x, av.y, av.z, av.w};
      float br[4] = {bv.x, bv.y, bv.z, bv.w};
      #pragma unroll
      for (int i = 0; i < 4; i++)
        #pragma unroll
        for (int j = 0; j < 4; j++)
          acc[i][j] = fmaf(ar[i], br[j], acc[i][j]);
    }
    __syncthreads();
  }
  #pragma unroll
  for (int i = 0; i < 4; i++) {
    float4 o4; o4.x = acc[i][0]; o4.y = acc[i][1]; o4.z = acc[i][2]; o4.w = acc[i][3];
    *(float4*)(C + (size_t)(rb + r0 + i) * 1024 + cb + c0) = o4;
  }
}

// ======================== ballot radix-select helpers =======================
__device__ inline unsigned f2ord(float f) {
  unsigned u = __float_as_uint(f);
  return (u & 0x80000000u) ? ~u : (u | 0x80000000u);
}
__device__ inline int lpc(unsigned long long m) {
  return __builtin_amdgcn_mbcnt_hi((unsigned)(m >> 32),
         __builtin_amdgcn_mbcnt_lo((unsigned)m, 0));
}

// ======= K3: fused tail (R7 form): select w/ early-exit, then gather ========
__global__ __launch_bounds__(256) void tail_kernel(const float* __restrict__ sc,
                                                   const float* __restrict__ misc,
                                                   const float* __restrict__ core,
                                                   const float* __restrict__ memories,
                                                   float* __restrict__ out)
{
  __shared__ __align__(16) float s_pl[1024];
  __shared__ int   tkbuf[4][32];
  __shared__ float mvals[4][32];
  __shared__ int   mcand[4][32];
  __shared__ int   s_idx[64];
  __shared__ float s_w[64];

  const int row = blockIdx.x;
  const int tid = threadIdx.x;
  ((float4*)s_pl)[tid] = ((const float4*)(sc + (size_t)row * 1024))[tid];
  __syncthreads();

  const int w = tid >> 6, lane = tid & 63;

  // ---- phase 1: wave w -> (head = w>>1, side = w&1), top-32 of 256 ----
  {
    const int h = w >> 1, side = w & 1;
    const float v0 = misc[side * 4 + h * 2 + 0];
    const float v1 = misc[side * 4 + h * 2 + 1];
    const float* p0 = s_pl + side * 512;
    const float* p1 = p0 + 256;
    const int mb = lane * 4;
    float4 a4 = *(const float4*)(p0 + mb);
    float4 b4 = *(const float4*)(p1 + mb);
    unsigned kk[4];
    kk[0] = f2ord(a4.x * v0 + b4.x * v1);
    kk[1] = f2ord(a4.y * v0 + b4.y * v1);
    kk[2] = f2ord(a4.z * v0 + b4.z * v1);
    kk[3] = f2ord(a4.w * v0 + b4.w * v1);
    unsigned tau = 0u;
    for (int b = 31; b >= 0; --b) {
      unsigned cand = tau | (1u << b);
      int cnt = 0;
      #pragma unroll
      for (int i = 0; i < 4; i++) cnt += __popcll(__ballot(kk[i] >= cand));
      if (cnt >= 32) {
        tau = cand;
        if (cnt == 32) break;   // exact top-32 set determined
      }
    }
    unsigned long long bG[4], bE[4];
    int cntG = 0, sbG = 0, sbE = 0;
    #pragma unroll
    for (int i = 0; i < 4; i++) {
      bG[i] = __ballot(kk[i] > tau);
      bE[i] = __ballot(kk[i] == tau);
      cntG += __popcll(bG[i]);
      sbG  += lpc(bG[i]);
      sbE  += lpc(bE[i]);
    }
    const int need = 32 - cntG;
    int runG = 0, runE = 0;
    #pragma unroll
    for (int i = 0; i < 4; i++) {
      if (kk[i] > tau)       { tkbuf[w][sbG + runG] = mb + i; runG++; }
      else if (kk[i] == tau) {
        int r = sbE + runE;
        if (r < need) tkbuf[w][cntG + r] = mb + i;
        runE++;
      }
    }
  }
  __syncthreads();

  // ---- phase 2: wave w -> (head = w>>1, half = w&1), top-32 of 512 ----
  {
    const int h = w >> 1, half = w & 1;
    const float c00 = core[h * 4 + 0], c01 = core[h * 4 + 1];
    const float c10 = core[h * 4 + 2], c11 = core[h * 4 + 3];
    const int i_glob = half * 16 + (lane >> 2);
    const int ri = tkbuf[h * 2 + 0][i_glob];
    const float fr0 = s_pl[ri], fr1 = s_pl[256 + ri];
    const float a0 = fr0 * c00 + fr1 * c10;
    const float a1 = fr0 * c01 + fr1 * c11;
    const int j0 = (lane & 3) * 8;
    float sv[8];
    unsigned kk[8];
    #pragma unroll
    for (int t2 = 0; t2 < 8; t2++) {
      int cj = tkbuf[h * 2 + 1][j0 + t2];
      sv[t2] = a0 * s_pl[512 + cj] + a1 * s_pl[768 + cj];
      kk[t2] = f2ord(sv[t2]);
    }
    unsigned tau = 0u;
    for (int b = 31; b >= 0; --b) {
      unsigned cand = tau | (1u << b);
      int cnt = 0;
      #pragma unroll
      for (int i = 0; i < 8; i++) cnt += __popcll(__ballot(kk[i] >= cand));
      if (cnt >= 32) {
        tau = cand;
        if (cnt == 32) break;   // exact top-32 set determined
      }
    }
    unsigned long long bG[8], bE[8];
    int cntG = 0, sbG = 0, sbE = 0;
    #pragma unroll
    for (int i = 0; i < 8; i++) {
      bG[i] = __ballot(kk[i] > tau);
      bE[i] = __ballot(kk[i] == tau);
      cntG += __popcll(bG[i]);
      sbG  += lpc(bG[i]);
      sbE  += lpc(bE[i]);
    }
    const int need = 32 - cntG;
    int runG = 0, runE = 0;
    #pragma unroll
    for (int i = 0; i < 8; i++) {
      int c = i_glob * 32 + j0 + i;
      if (kk[i] > tau) {
        mvals[w][sbG + runG] = sv[i]; mcand[w][sbG + runG] = c; runG++;
      } else if (kk[i] == tau) {
        int r = sbE + runE;
        if (r < need) { mvals[w][cntG + r] = sv[i]; mcand[w][cntG + r] = c; }
        runE++;
      }
    }
  }
  __syncthreads();

  // ---- merge two half-lists per head by rank-count ----
  if (w < 2) {
    const int h = w;
    const int half2 = lane >> 5, k = lane & 31;
    const float v = mvals[h * 2 + half2][k];
    const int   c = mcand[h * 2 + half2][k];
    int cnt = 0;
    #pragma unroll 8
    for (int j = 0; j < 64; j++) {
      float u = mvals[h * 2 + (j >> 5)][j & 31];
      int  uc = mcand[h * 2 + (j >> 5)][j & 31];
      cnt += (u > v || (u == v && uc < c)) ? 1 : 0;
    }
    if (cnt < 32) {
      int ii = c >> 5, jj = c & 31;
      s_idx[h * 32 + cnt] = tkbuf[h * 2][ii] * 256 + tkbuf[h * 2 + 1][jj];
      s_w[h * 32 + cnt]   = 1.0f / (1.0f + expf(-v));
    }
  }
  __syncthreads();

  // ---- weighted gather-sum: double-buffered batches of 8 loads ----
  const int h2 = tid >> 7;
  const int d4 = tid & 127;
  const int base = h2 * 32;
  const float* mb = memories + d4 * 4;
  float ax = 0.f, ay = 0.f, az = 0.f, aw = 0.f;
  float4 va[8], vb[8];
  float  wa[8], wb[8];
  #pragma unroll
  for (int i = 0; i < 8; i++) {
    int mi = s_idx[base + i]; wa[i] = s_w[base + i];
    va[i] = *(const float4*)(mb + (size_t)mi * 512);
  }
  #pragma unroll
  for (int i = 0; i < 8; i++) {
    int mi = s_idx[base + 8 + i]; wb[i] = s_w[base + 8 + i];
    vb[i] = *(const float4*)(mb + (size_t)mi * 512);
  }
  #pragma unroll
  for (int i = 0; i < 8; i++) {
    ax = fmaf(wa[i], va[i].x, ax); ay = fmaf(wa[i], va[i].y, ay);
    az = fmaf(wa[i], va[i].z, az); aw = fmaf(wa[i], va[i].w, aw);
  }
  #pragma unroll
  for (int i = 0; i < 8; i++) {
    int mi = s_idx[base + 16 + i]; wa[i] = s_w[base + 16 + i];
    va[i] = *(const float4*)(mb + (size_t)mi * 512);
  }
  #pragma unroll
  for (int i = 0; i < 8; i++) {
    ax = fmaf(wb[i], vb[i].x, ax); ay = fmaf(wb[i], vb[i].y, ay);
    az = fmaf(wb[i], vb[i].z, az); aw = fmaf(wb[i], vb[i].w, aw);
  }
  #pragma unroll
  for (int i = 0; i < 8; i++) {
    int mi = s_idx[base + 24 + i]; wb[i] = s_w[base + 24 + i];
    vb[i] = *(const float4*)(mb + (size_t)mi * 512);
  }
  #pragma unroll
  for (int i = 0; i < 8; i++) {
    ax = fmaf(wa[i], va[i].x, ax); ay = fmaf(wa[i], va[i].y, ay);
    az = fmaf(wa[i], va[i].z, az); aw = fmaf(wa[i], va[i].w, aw);
  }
  #pragma unroll
  for (int i = 0; i < 8; i++) {
    ax = fmaf(wb[i], vb[i].x, ax); ay = fmaf(wb[i], vb[i].y, ay);
    az = fmaf(wb[i], vb[i].z, az); aw = fmaf(wb[i], vb[i].w, aw);
  }
  float4 o4; o4.x = ax; o4.y = ay; o4.z = az; o4.w = aw;
  ((float4*)out)[(size_t)row * 256 + tid] = o4;
}

// ============================== launcher ====================================
extern "C" void kernel_launch(void* const* d_in, const int* in_sizes, int n_in,
                              void* d_out, int out_size, void* d_ws, size_t ws_size,
                              hipStream_t stream) {
  const float* tokens = (const float*)d_in[0];
  const float* rms_w  = (const float*)d_in[1];
  const float* conv_w = (const float*)d_in[2];
  const float* conv_b = (const float*)d_in[3];
  const float* wq     = (const float*)d_in[4];
  const float* qln_w  = (const float*)d_in[5];
  const float* keys   = (const float*)d_in[6];
  const float* core   = (const float*)d_in[7];
  const float* mems   = (const float*)d_in[8];
  float* out = (float*)d_out;
  float* ws  = (float*)d_ws;

  // workspace layout (floats)
  float* misc  = ws;                       // 8
  float* invs  = ws + 1024;                // 2048
  float* qpart = ws + 4096;                // KSPLIT * 2048*128 = 2,097,152
  float* sc    = qpart + 2097152;          // 2048*1024

  rms_kernel     <<<ROWS / 8, 256, 0, stream>>>(tokens, core, invs, misc,
                                                out + 2097152);
  convgemm1_kernel<<<dim3(64, KSPLIT), 256, 0, stream>>>(tokens, invs, rms_w,
                                                         conv_w, conv_b, wq, qpart);
  gemm2ln_kernel <<<dim3(64, 8), 256, 0, stream>>>(qpart, qln_w, keys, sc);
  tail_kernel    <<<ROWS, 256, 0, stream>>>(sc, misc, core, mems, out);
}